// Round 6
// baseline (272.434 us; speedup 1.0000x reference)
//
#include <hip/hip_runtime.h>
#include <hip/hip_bf16.h>
#include <math.h>

#define NTOK 4096
#define DIM 2048
#define NHEAD 1002
#define NCAT 1664
#define C0LO 1000
#define C0HI 10000
#define OSZ0 9000
#define OSZ1 40257
#define H0S 512
#define H1S 128
#define JS0 32               // tail0 j-slices (1024 blocks -> 4 blocks/CU at 33KB LDS)
#define JS1 16               // tail1 j-slices (512 blocks, 66KB LDS -> 2 blocks/CU)
#define HEADBLKS 8
#define NT0 71               // ceil(9000/128)
#define NT1 315              // ceil(40257/128)

typedef __attribute__((ext_vector_type(4))) short short4v;
typedef __attribute__((ext_vector_type(8))) short short8v;
typedef __attribute__((ext_vector_type(4))) float f32x4;
typedef __hip_bfloat16 bf16;

#define GLOBAL_AS __attribute__((address_space(1)))
#define LDS_AS __attribute__((address_space(3)))

#define RAW_BAR() __builtin_amdgcn_s_barrier()
#define SCHED_FENCE() __builtin_amdgcn_sched_barrier(0)
#define WAIT_VM(N) asm volatile("s_waitcnt vmcnt(" #N ")" ::: "memory")
#define WAIT_LGKM0() asm volatile("s_waitcnt lgkmcnt(0)" ::: "memory")

// ---------- fused fp32->bf16 convert + Wcat concat ----------
__global__ __launch_bounds__(256) void cvt_all(
    const float* __restrict__ x, const float* __restrict__ W_head,
    const float* __restrict__ W1_0, const float* __restrict__ W1_1,
    const float* __restrict__ W2_0, const float* __restrict__ W2_1,
    bf16* __restrict__ xb, bf16* __restrict__ Wcat,
    bf16* __restrict__ W20b, bf16* __restrict__ W21b) {
  const long NX = (long)NTOK * DIM / 8;
  const long NC = (long)NCAT * DIM / 8;
  const long N20 = (long)OSZ0 * H0S / 8;
  const long N21 = (long)OSZ1 * H1S / 8;
  long gid = (long)blockIdx.x * 256 + threadIdx.x;
  const float* src = nullptr;
  bf16* dst;
  if (gid < NX) {
    src = x + gid * 8; dst = xb + gid * 8;
  } else if (gid < NX + NC) {
    long o = (gid - NX) * 8;
    int row = (int)(o >> 11), k = (int)(o & 2047);
    dst = Wcat + o;
    if (row < NHEAD) src = W_head + (long)row * DIM + k;
    else if (row < 1024) src = nullptr;              // zero padding rows
    else if (row < 1536) src = W1_0 + (long)(row - 1024) * DIM + k;
    else src = W1_1 + (long)(row - 1536) * DIM + k;
  } else if (gid < NX + NC + N20) {
    long o = (gid - NX - NC) * 8; src = W2_0 + o; dst = W20b + o;
  } else if (gid < NX + NC + N20 + N21) {
    long o = (gid - NX - NC - N20) * 8; src = W2_1 + o; dst = W21b + o;
  } else {
    return;
  }
  union { short8v v; bf16 h[8]; } u;
  if (src) {
    float4 a = *reinterpret_cast<const float4*>(src);
    float4 b = *reinterpret_cast<const float4*>(src + 4);
    u.h[0] = __float2bfloat16(a.x); u.h[1] = __float2bfloat16(a.y);
    u.h[2] = __float2bfloat16(a.z); u.h[3] = __float2bfloat16(a.w);
    u.h[4] = __float2bfloat16(b.x); u.h[5] = __float2bfloat16(b.y);
    u.h[6] = __float2bfloat16(b.z); u.h[7] = __float2bfloat16(b.w);
  } else {
#pragma unroll
    for (int e = 0; e < 8; ++e) u.h[e] = __float2bfloat16(0.f);
  }
  *reinterpret_cast<short8v*>(dst) = u.v;
}

// ---------- 128B-row staging (BK=64 slice), verified R2/R3 ----------
__device__ __forceinline__ void stage_tile(const bf16* __restrict__ g, int row0,
                                           int maxrow, int ld, int k0,
                                           char* lds, int wave, int lane) {
#pragma unroll
  for (int c = 0; c < 4; ++c) {
    int rbase = wave * 32 + c * 8;
    int row = rbase + (lane >> 3);
    int grow = row0 + row;
    grow = grow < maxrow ? grow : maxrow;
    int slot = (lane & 7) ^ (row & 7);
    const bf16* src = g + (size_t)grow * ld + k0 + slot * 8;
    __builtin_amdgcn_global_load_lds((const GLOBAL_AS unsigned int*)src,
                                     (LDS_AS unsigned int*)(lds + rbase * 128),
                                     16, 0, 0);
  }
}

__device__ __forceinline__ short8v read_frag(const char* lds, int row, int kk, int lane) {
  int g = lane >> 4;
  int r7 = row & 7;
  int b1 = kk * 64 + g * 8;
  int b2 = b1 + 32;
  b1 = ((b1 >> 4) ^ r7) * 16 + (b1 & 15);
  b2 = ((b2 >> 4) ^ r7) * 16 + (b2 & 15);
  const char* p = lds + row * 128;
  short4v lo = *reinterpret_cast<const short4v*>(p + b1);
  short4v hi = *reinterpret_cast<const short4v*>(p + b2);
  return __builtin_shufflevector(lo, hi, 0, 1, 2, 3, 4, 5, 6, 7);
}

// ---------- 256B-row staging (whole K=128 tile, tail1) ----------
__device__ __forceinline__ void stage_tile256(const bf16* __restrict__ g, int row0,
                                              int maxrow, int ld,
                                              char* lds, int wave, int lane) {
#pragma unroll
  for (int c = 0; c < 8; ++c) {
    int rbase = wave * 32 + c * 4;
    int row = rbase + (lane >> 4);
    int grow = row0 + row;
    grow = grow < maxrow ? grow : maxrow;
    int slot = (lane & 15) ^ (row & 7);
    const bf16* src = g + (size_t)grow * ld + slot * 8;
    __builtin_amdgcn_global_load_lds((const GLOBAL_AS unsigned int*)src,
                                     (LDS_AS unsigned int*)(lds + rbase * 256),
                                     16, 0, 0);
  }
}

__device__ __forceinline__ short8v read_frag256(const char* lds, int row, int kk, int lane) {
  int g = lane >> 4;
  int r7 = row & 7;
  int b1 = kk * 64 + g * 8;
  int b2 = b1 + 32;
  b1 = (((b1 >> 4) ^ r7) << 4) | (b1 & 15);
  b2 = (((b2 >> 4) ^ r7) << 4) | (b2 & 15);
  const char* p = lds + row * 256;
  short4v lo = *reinterpret_cast<const short4v*>(p + b1);
  short4v hi = *reinterpret_cast<const short4v*>(p + b2);
  return __builtin_shufflevector(lo, hi, 0, 1, 2, 3, 4, 5, 6, 7);
}

// shared sum-exp tree reduce + partial-sum write (layout identical R2/R3)
__device__ __forceinline__ void reduce_write_ps(float srun[4][4], float* reds,
                                                float* ps, int slice, int tok0,
                                                int lane, int wr, int wc) {
#pragma unroll
  for (int off = 1; off < 16; off <<= 1)
#pragma unroll
    for (int m = 0; m < 4; ++m)
#pragma unroll
      for (int r = 0; r < 4; ++r) srun[m][r] += __shfl_xor(srun[m][r], off);
  __syncthreads();
  if (wc == 0 && (lane & 15) == 0) {
#pragma unroll
    for (int m = 0; m < 4; ++m)
#pragma unroll
      for (int r = 0; r < 4; ++r)
        reds[wr * 64 + m * 16 + (lane >> 4) * 4 + r] = srun[m][r];
  }
  __syncthreads();
  if (wc == 1 && (lane & 15) == 0) {
#pragma unroll
    for (int m = 0; m < 4; ++m)
#pragma unroll
      for (int r = 0; r < 4; ++r) {
        int row = wr * 64 + m * 16 + (lane >> 4) * 4 + r;
        ps[(size_t)slice * NTOK + tok0 + row] = reds[row] + srun[m][r];
      }
  }
}

// ---------- tail0 (H=512): R3-verified 2-barrier structure, 33KB LDS ----------
// JS0=32 -> 1024 blocks -> 4 resident blocks/CU (grid was the occupancy cap).
__global__ __launch_bounds__(256, 4) void tail0_lse(
    const bf16* __restrict__ Ab, const bf16* __restrict__ W2b,
    float* __restrict__ ps) {
  __shared__ __align__(16) char As[128 * 128];
  __shared__ __align__(16) char Bs[128 * 128];
  __shared__ float reds[128];
  int tid = threadIdx.x;
  int lane = tid & 63, wave = tid >> 6;
  int wr = wave >> 1, wc = wave & 1;
  int tok0 = blockIdx.x * 128;
  int ys = blockIdx.y;
  int t_lo = (NT0 * ys) / JS0, t_hi = (NT0 * (ys + 1)) / JS0;
  float srun[4][4] = {};
  for (int jt = t_lo; jt < t_hi; ++jt) {
    int j0 = jt * 128;
    f32x4 acc[4][4] = {};
    for (int k0 = 0; k0 < H0S; k0 += 64) {
      __syncthreads();
      stage_tile(Ab, tok0, NTOK - 1, H0S, k0, As, wave, lane);
      stage_tile(W2b, j0, OSZ0 - 1, H0S, k0, Bs, wave, lane);
      __syncthreads();
#pragma unroll
      for (int kk = 0; kk < 2; ++kk) {
        short8v af[4], bfr[4];
#pragma unroll
        for (int m = 0; m < 4; ++m)
          af[m] = read_frag(As, wr * 64 + m * 16 + (lane & 15), kk, lane);
#pragma unroll
        for (int n = 0; n < 4; ++n)
          bfr[n] = read_frag(Bs, wc * 64 + n * 16 + (lane & 15), kk, lane);
#pragma unroll
        for (int m = 0; m < 4; ++m)
#pragma unroll
          for (int n = 0; n < 4; ++n)
            acc[m][n] = __builtin_amdgcn_mfma_f32_16x16x32_bf16(af[m], bfr[n], acc[m][n], 0, 0, 0);
      }
    }
#pragma unroll
    for (int m = 0; m < 4; ++m)
#pragma unroll
      for (int n = 0; n < 4; ++n) {
        int col = j0 + wc * 64 + n * 16 + (lane & 15);
        if (col < OSZ0) {
#pragma unroll
          for (int r = 0; r < 4; ++r) srun[m][r] += __expf(acc[m][n][r]);
        }
      }
  }
  reduce_write_ps(srun, reds, ps, ys, tok0, lane, wr, wc);
}

// ---------- tail1 (H=128): A-in-regs, dbuf B stream (R3-verified) ----------
__device__ void tail1_body(const bf16* __restrict__ Ab, const bf16* __restrict__ W2b,
                           float* __restrict__ ps, char* lds) {
  char* buf0 = lds;             // 32 KB
  char* buf1 = lds + 32768;     // 32 KB
  float* reds = (float*)(lds + 65536);
  int tid = threadIdx.x;
  int lane = tid & 63, wave = tid >> 6;
  int wr = wave >> 1, wc = wave & 1;
  int tok0 = blockIdx.x * 128;
  int ys = blockIdx.y;
  int t_lo = (NT1 * ys) / JS1, t_hi = (NT1 * (ys + 1)) / JS1;
  int nt = t_hi - t_lo;

  stage_tile256(Ab, tok0, NTOK - 1, H1S, buf1, wave, lane);
  WAIT_VM(0); SCHED_FENCE();
  RAW_BAR();
  short8v afr[4][4];
#pragma unroll
  for (int kk = 0; kk < 4; ++kk)
#pragma unroll
    for (int m = 0; m < 4; ++m)
      afr[kk][m] = read_frag256(buf1, wr * 64 + m * 16 + (lane & 15), kk, lane);
  stage_tile256(W2b, t_lo * 128, OSZ1 - 1, H1S, buf0, wave, lane);
  WAIT_LGKM0(); SCHED_FENCE();   // A-frag reads done before buf1 reuse
  RAW_BAR();
  if (nt > 1) stage_tile256(W2b, (t_lo + 1) * 128, OSZ1 - 1, H1S, buf1, wave, lane);

  float srun[4][4] = {};
  for (int i = 0; i < nt; ++i) {
    char* cur = (i & 1) ? buf1 : buf0;
    if (i + 1 < nt) { WAIT_VM(8); } else { WAIT_VM(0); }
    SCHED_FENCE();
    RAW_BAR();
    int j0 = (t_lo + i) * 128;
    f32x4 acc[4][4] = {};
#pragma unroll
    for (int kk = 0; kk < 4; ++kk) {
      short8v bfr[4];
#pragma unroll
      for (int n = 0; n < 4; ++n)
        bfr[n] = read_frag256(cur, wc * 64 + n * 16 + (lane & 15), kk, lane);
#pragma unroll
      for (int m = 0; m < 4; ++m)
#pragma unroll
        for (int n = 0; n < 4; ++n)
          acc[m][n] = __builtin_amdgcn_mfma_f32_16x16x32_bf16(afr[kk][m], bfr[n], acc[m][n], 0, 0, 0);
    }
#pragma unroll
    for (int m = 0; m < 4; ++m)
#pragma unroll
      for (int n = 0; n < 4; ++n) {
        int col = j0 + wc * 64 + n * 16 + (lane & 15);
        if (col < OSZ1) {
#pragma unroll
          for (int r = 0; r < 4; ++r) srun[m][r] += __expf(acc[m][n][r]);
        }
      }
    SCHED_FENCE();
    RAW_BAR();
    if (i + 2 < nt) stage_tile256(W2b, (t_lo + i + 2) * 128, OSZ1 - 1, H1S, cur, wave, lane);
  }
  reduce_write_ps(srun, reds, ps, ys, tok0, lane, wr, wc);
}

__global__ __launch_bounds__(256, 2) void tail1_lse(
    const bf16* __restrict__ Ab, const bf16* __restrict__ W2b,
    float* __restrict__ ps) {
  __shared__ __align__(16) char lds[66048];
  tail1_body(Ab, W2b, ps, lds);
}

// ---------- fused projection GEMM, dbuf counted-vmcnt (R5-verified) ----------
__device__ void proj_gemm_body(
    const bf16* __restrict__ A, const bf16* __restrict__ B,
    float* __restrict__ head, float* __restrict__ h0, bf16* __restrict__ h0b,
    float* __restrict__ h1, bf16* __restrict__ h1b, float* __restrict__ ps_head,
    char* lds) {
  char* Abuf[2] = {lds, lds + 16384};
  char* Bbuf[2] = {lds + 32768, lds + 49152};
  float* reds = (float*)(lds + 65536);
  int tid = threadIdx.x;
  int lane = tid & 63, wave = tid >> 6;
  int wr = wave >> 1, wc = wave & 1;
  int row0 = blockIdx.y * 128, col0 = blockIdx.x * 128;
  const int NIT = DIM / 64;  // 32
  stage_tile(A, row0, NTOK - 1, DIM, 0, Abuf[0], wave, lane);
  stage_tile(B, col0, NCAT - 1, DIM, 0, Bbuf[0], wave, lane);
  stage_tile(A, row0, NTOK - 1, DIM, 64, Abuf[1], wave, lane);
  stage_tile(B, col0, NCAT - 1, DIM, 64, Bbuf[1], wave, lane);
  f32x4 acc[4][4] = {};
  for (int it = 0; it < NIT; ++it) {
    char* Ac = Abuf[it & 1];
    char* Bc = Bbuf[it & 1];
    if (it + 1 < NIT) { WAIT_VM(8); } else { WAIT_VM(0); }
    SCHED_FENCE();
    RAW_BAR();
#pragma unroll
    for (int kk = 0; kk < 2; ++kk) {
      short8v af[4], bfr[4];
#pragma unroll
      for (int m = 0; m < 4; ++m)
        af[m] = read_frag(Ac, wr * 64 + m * 16 + (lane & 15), kk, lane);
#pragma unroll
      for (int n = 0; n < 4; ++n)
        bfr[n] = read_frag(Bc, wc * 64 + n * 16 + (lane & 15), kk, lane);
#pragma unroll
      for (int m = 0; m < 4; ++m)
#pragma unroll
        for (int n = 0; n < 4; ++n)
          acc[m][n] = __builtin_amdgcn_mfma_f32_16x16x32_bf16(af[m], bfr[n], acc[m][n], 0, 0, 0);
    }
    SCHED_FENCE();
    RAW_BAR();
    if (it + 2 < NIT) {
      stage_tile(A, row0, NTOK - 1, DIM, (it + 2) * 64, Ac, wave, lane);
      stage_tile(B, col0, NCAT - 1, DIM, (it + 2) * 64, Bc, wave, lane);
    }
  }
  float srun[4][4] = {};
#pragma unroll
  for (int m = 0; m < 4; ++m) {
    int row = row0 + wr * 64 + m * 16 + (lane >> 4) * 4;
#pragma unroll
    for (int n = 0; n < 4; ++n) {
      int col = col0 + wc * 64 + n * 16 + (lane & 15);
#pragma unroll
      for (int r = 0; r < 4; ++r) {
        float v = acc[m][n][r];
        if (col < NHEAD) {
          head[(size_t)(row + r) * NHEAD + col] = v;
          srun[m][r] += __expf(v);
        } else if (col >= 1024 && col < 1536) {
          h0[(size_t)(row + r) * H0S + (col - 1024)] = v;
          h0b[(size_t)(row + r) * H0S + (col - 1024)] = __float2bfloat16(v);
        } else if (col >= 1536) {
          h1[(size_t)(row + r) * H1S + (col - 1536)] = v;
          h1b[(size_t)(row + r) * H1S + (col - 1536)] = __float2bfloat16(v);
        }
      }
    }
  }
  if (blockIdx.x < HEADBLKS) {
    reduce_write_ps(srun, reds, ps_head, blockIdx.x, row0, lane, wr, wc);
  }
}

__global__ __launch_bounds__(256, 2) void proj_gemm(
    const bf16* __restrict__ A, const bf16* __restrict__ B,
    float* __restrict__ head, float* __restrict__ h0, bf16* __restrict__ h0b,
    float* __restrict__ h1, bf16* __restrict__ h1b, float* __restrict__ ps_head) {
  __shared__ __align__(16) char lds[66048];
  proj_gemm_body(A, B, head, h0, h0b, h1, h1b, ps_head, lds);
}

// ---------- finalize: one wave per token ----------
__global__ __launch_bounds__(256) void finalize2(
    const int* __restrict__ target, const float* __restrict__ head,
    const float* __restrict__ ps_head,
    const float* __restrict__ h0, const float* __restrict__ h1,
    const float* __restrict__ W2_0, const float* __restrict__ W2_1,
    const float* __restrict__ ps0, const float* __restrict__ ps1,
    float* __restrict__ out) {
  int warp = threadIdx.x >> 6, lane = threadIdx.x & 63;
  int i = blockIdx.x * 4 + warp;
  if (i >= NTOK) return;
  int t = target[i];
  float sh = 0.f;
#pragma unroll
  for (int s = 0; s < HEADBLKS; ++s) sh += ps_head[(size_t)s * NTOK + i];
  float lse_head = logf(sh);
  float res;
  if (t < C0LO) {
    res = head[(size_t)i * NHEAD + t] - lse_head;
  } else {
    int c = (t < C0HI) ? 0 : 1;
    int H = c ? H1S : H0S;
    int low = c ? C0HI : C0LO;
    const float* hv = (c ? h1 : h0) + (size_t)i * H;
    const float* wv = (c ? W2_1 : W2_0) + (size_t)(t - low) * H;
    float p = 0.f;
    for (int k = lane * 4; k < H; k += 256) {
      float4 a = *reinterpret_cast<const float4*>(hv + k);
      float4 b = *reinterpret_cast<const float4*>(wv + k);
      p += a.x * b.x + a.y * b.y + a.z * b.z + a.w * b.w;
    }
#pragma unroll
    for (int off = 32; off > 0; off >>= 1) p += __shfl_xor(p, off);
    const float* ps = c ? ps1 : ps0;
    int js = c ? JS1 : JS0;   // per-cluster slice count (JS0 != JS1 now)
    float S = 0.f;
    for (int s = 0; s < js; ++s) S += ps[(size_t)s * NTOK + i];
    float cl = head[(size_t)i * NHEAD + C0LO + c];
    res = (cl - lse_head) + (p - logf(S));
  }
  if (lane == 0) out[i] = res;
}

__global__ __launch_bounds__(256) void loss_kernel(float* __restrict__ out) {
  __shared__ float red[256];
  int tid = threadIdx.x;
  float s = 0.f;
  for (int j = tid; j < NTOK; j += 256) s += out[j];
  red[tid] = s; __syncthreads();
  for (int off = 128; off > 0; off >>= 1) {
    if (tid < off) red[tid] += red[tid + off];
    __syncthreads();
  }
  if (tid == 0) out[NTOK] = -red[0] / (float)NTOK;
}

extern "C" void kernel_launch(void* const* d_in, const int* in_sizes, int n_in,
                              void* d_out, int out_size, void* d_ws, size_t ws_size,
                              hipStream_t stream) {
  (void)in_sizes; (void)n_in; (void)out_size; (void)ws_size;
  const float* x = (const float*)d_in[0];
  const int* target = (const int*)d_in[1];
  const float* W_head = (const float*)d_in[2];
  const float* W1_0 = (const float*)d_in[3];
  const float* W2_0 = (const float*)d_in[4];
  const float* W1_1 = (const float*)d_in[5];
  const float* W2_1 = (const float*)d_in[6];
  float* out = (float*)d_out;

  char* w = (char*)d_ws;
  size_t off = 0;
  auto alloc = [&](size_t bytes) -> void* {
    void* p = w + off;
    off = (off + bytes + 255) & ~(size_t)255;
    return p;
  };
  bf16* xb   = (bf16*)alloc((size_t)NTOK * DIM * 2);
  bf16* Wcat = (bf16*)alloc((size_t)NCAT * DIM * 2);
  bf16* W20b = (bf16*)alloc((size_t)OSZ0 * H0S * 2);
  bf16* W21b = (bf16*)alloc((size_t)OSZ1 * H1S * 2);
  float* head = (float*)alloc((size_t)NTOK * NHEAD * 4);
  float* h0   = (float*)alloc((size_t)NTOK * H0S * 4);
  bf16*  h0b  = (bf16*)alloc((size_t)NTOK * H0S * 2);
  float* h1   = (float*)alloc((size_t)NTOK * H1S * 4);
  bf16*  h1b  = (bf16*)alloc((size_t)NTOK * H1S * 2);
  float* ps_head = (float*)alloc((size_t)HEADBLKS * NTOK * 4);
  float* ps0 = (float*)alloc((size_t)JS0 * NTOK * 4);
  float* ps1 = (float*)alloc((size_t)JS1 * NTOK * 4);

  dim3 blk(256);
  const long TOT8 = (long)NTOK * DIM / 8 + (long)NCAT * DIM / 8 +
                    (long)OSZ0 * H0S / 8 + (long)OSZ1 * H1S / 8;
  cvt_all<<<dim3((unsigned)((TOT8 + 255) / 256)), blk, 0, stream>>>(
      x, W_head, W1_0, W1_1, W2_0, W2_1, xb, Wcat, W20b, W21b);

  proj_gemm<<<dim3(NCAT / 128, NTOK / 128), blk, 0, stream>>>(
      xb, Wcat, head, h0, h0b, h1, h1b, ps_head);

  tail0_lse<<<dim3(NTOK / 128, JS0), blk, 0, stream>>>(h0b, W20b, ps0);
  tail1_lse<<<dim3(NTOK / 128, JS1), blk, 0, stream>>>(h1b, W21b, ps1);

  finalize2<<<dim3(NTOK / 4), blk, 0, stream>>>(target, head, ps_head, h0, h1,
                                                W2_0, W2_1, ps0, ps1, out);
  loss_kernel<<<1, blk, 0, stream>>>(out);
}

// Round 7
// 239.769 us; speedup vs baseline: 1.1362x; 1.1362x over previous
//
#include <hip/hip_runtime.h>
#include <hip/hip_bf16.h>
#include <math.h>

#define NTOK 4096
#define DIM 2048
#define NHEAD 1002
#define NCAT 1664
#define C0LO 1000
#define C0HI 10000
#define OSZ0 9000
#define OSZ1 40257
#define H0S 512
#define H1S 128
#define JS0 24               // tail0 j-slices: 768 blocks -> 3 blocks/CU @ 33KB LDS, (256,3)
#define JS1 16               // tail1 j-slices (512 blocks, 66KB LDS -> 2 blocks/CU)
#define HEADBLKS 8
#define NT0 71               // ceil(9000/128)
#define NT1 315              // ceil(40257/128)

typedef __attribute__((ext_vector_type(4))) short short4v;
typedef __attribute__((ext_vector_type(8))) short short8v;
typedef __attribute__((ext_vector_type(4))) float f32x4;
typedef __hip_bfloat16 bf16;

#define GLOBAL_AS __attribute__((address_space(1)))
#define LDS_AS __attribute__((address_space(3)))

#define RAW_BAR() __builtin_amdgcn_s_barrier()
#define SCHED_FENCE() __builtin_amdgcn_sched_barrier(0)
#define WAIT_VM(N) asm volatile("s_waitcnt vmcnt(" #N ")" ::: "memory")
#define WAIT_LGKM0() asm volatile("s_waitcnt lgkmcnt(0)" ::: "memory")

// ---------- fused fp32->bf16 convert + Wcat concat ----------
__global__ __launch_bounds__(256) void cvt_all(
    const float* __restrict__ x, const float* __restrict__ W_head,
    const float* __restrict__ W1_0, const float* __restrict__ W1_1,
    const float* __restrict__ W2_0, const float* __restrict__ W2_1,
    bf16* __restrict__ xb, bf16* __restrict__ Wcat,
    bf16* __restrict__ W20b, bf16* __restrict__ W21b) {
  const long NX = (long)NTOK * DIM / 8;
  const long NC = (long)NCAT * DIM / 8;
  const long N20 = (long)OSZ0 * H0S / 8;
  const long N21 = (long)OSZ1 * H1S / 8;
  long gid = (long)blockIdx.x * 256 + threadIdx.x;
  const float* src = nullptr;
  bf16* dst;
  if (gid < NX) {
    src = x + gid * 8; dst = xb + gid * 8;
  } else if (gid < NX + NC) {
    long o = (gid - NX) * 8;
    int row = (int)(o >> 11), k = (int)(o & 2047);
    dst = Wcat + o;
    if (row < NHEAD) src = W_head + (long)row * DIM + k;
    else if (row < 1024) src = nullptr;              // zero padding rows
    else if (row < 1536) src = W1_0 + (long)(row - 1024) * DIM + k;
    else src = W1_1 + (long)(row - 1536) * DIM + k;
  } else if (gid < NX + NC + N20) {
    long o = (gid - NX - NC) * 8; src = W2_0 + o; dst = W20b + o;
  } else if (gid < NX + NC + N20 + N21) {
    long o = (gid - NX - NC - N20) * 8; src = W2_1 + o; dst = W21b + o;
  } else {
    return;
  }
  union { short8v v; bf16 h[8]; } u;
  if (src) {
    float4 a = *reinterpret_cast<const float4*>(src);
    float4 b = *reinterpret_cast<const float4*>(src + 4);
    u.h[0] = __float2bfloat16(a.x); u.h[1] = __float2bfloat16(a.y);
    u.h[2] = __float2bfloat16(a.z); u.h[3] = __float2bfloat16(a.w);
    u.h[4] = __float2bfloat16(b.x); u.h[5] = __float2bfloat16(b.y);
    u.h[6] = __float2bfloat16(b.z); u.h[7] = __float2bfloat16(b.w);
  } else {
#pragma unroll
    for (int e = 0; e < 8; ++e) u.h[e] = __float2bfloat16(0.f);
  }
  *reinterpret_cast<short8v*>(dst) = u.v;
}

// ---------- 128B-row staging (BK=64 slice), verified R2/R3 ----------
__device__ __forceinline__ void stage_tile(const bf16* __restrict__ g, int row0,
                                           int maxrow, int ld, int k0,
                                           char* lds, int wave, int lane) {
#pragma unroll
  for (int c = 0; c < 4; ++c) {
    int rbase = wave * 32 + c * 8;
    int row = rbase + (lane >> 3);
    int grow = row0 + row;
    grow = grow < maxrow ? grow : maxrow;
    int slot = (lane & 7) ^ (row & 7);
    const bf16* src = g + (size_t)grow * ld + k0 + slot * 8;
    __builtin_amdgcn_global_load_lds((const GLOBAL_AS unsigned int*)src,
                                     (LDS_AS unsigned int*)(lds + rbase * 128),
                                     16, 0, 0);
  }
}

__device__ __forceinline__ short8v read_frag(const char* lds, int row, int kk, int lane) {
  int g = lane >> 4;
  int r7 = row & 7;
  int b1 = kk * 64 + g * 8;
  int b2 = b1 + 32;
  b1 = ((b1 >> 4) ^ r7) * 16 + (b1 & 15);
  b2 = ((b2 >> 4) ^ r7) * 16 + (b2 & 15);
  const char* p = lds + row * 128;
  short4v lo = *reinterpret_cast<const short4v*>(p + b1);
  short4v hi = *reinterpret_cast<const short4v*>(p + b2);
  return __builtin_shufflevector(lo, hi, 0, 1, 2, 3, 4, 5, 6, 7);
}

// ---------- 256B-row staging (whole K=128 tile, tail1) ----------
__device__ __forceinline__ void stage_tile256(const bf16* __restrict__ g, int row0,
                                              int maxrow, int ld,
                                              char* lds, int wave, int lane) {
#pragma unroll
  for (int c = 0; c < 8; ++c) {
    int rbase = wave * 32 + c * 4;
    int row = rbase + (lane >> 4);
    int grow = row0 + row;
    grow = grow < maxrow ? grow : maxrow;
    int slot = (lane & 15) ^ (row & 7);
    const bf16* src = g + (size_t)grow * ld + slot * 8;
    __builtin_amdgcn_global_load_lds((const GLOBAL_AS unsigned int*)src,
                                     (LDS_AS unsigned int*)(lds + rbase * 256),
                                     16, 0, 0);
  }
}

__device__ __forceinline__ short8v read_frag256(const char* lds, int row, int kk, int lane) {
  int g = lane >> 4;
  int r7 = row & 7;
  int b1 = kk * 64 + g * 8;
  int b2 = b1 + 32;
  b1 = (((b1 >> 4) ^ r7) << 4) | (b1 & 15);
  b2 = (((b2 >> 4) ^ r7) << 4) | (b2 & 15);
  const char* p = lds + row * 256;
  short4v lo = *reinterpret_cast<const short4v*>(p + b1);
  short4v hi = *reinterpret_cast<const short4v*>(p + b2);
  return __builtin_shufflevector(lo, hi, 0, 1, 2, 3, 4, 5, 6, 7);
}

// shared sum-exp tree reduce + partial-sum write (layout identical R2/R3)
__device__ __forceinline__ void reduce_write_ps(float srun[4][4], float* reds,
                                                float* ps, int slice, int tok0,
                                                int lane, int wr, int wc) {
#pragma unroll
  for (int off = 1; off < 16; off <<= 1)
#pragma unroll
    for (int m = 0; m < 4; ++m)
#pragma unroll
      for (int r = 0; r < 4; ++r) srun[m][r] += __shfl_xor(srun[m][r], off);
  __syncthreads();
  if (wc == 0 && (lane & 15) == 0) {
#pragma unroll
    for (int m = 0; m < 4; ++m)
#pragma unroll
      for (int r = 0; r < 4; ++r)
        reds[wr * 64 + m * 16 + (lane >> 4) * 4 + r] = srun[m][r];
  }
  __syncthreads();
  if (wc == 1 && (lane & 15) == 0) {
#pragma unroll
    for (int m = 0; m < 4; ++m)
#pragma unroll
      for (int r = 0; r < 4; ++r) {
        int row = wr * 64 + m * 16 + (lane >> 4) * 4 + r;
        ps[(size_t)slice * NTOK + tok0 + row] = reds[row] + srun[m][r];
      }
  }
}

// ---------- tail0 (H=512): R3-verified 2-barrier structure, 33KB LDS ----------
// (256,3): unified reg budget 170/wave >= 152 needed (88 VGPR + 64 acc AGPR).
// (256,4) = budget 128 -> scratch spill -> 117MB WRITE_SIZE, 1.6x slowdown (R6).
__global__ __launch_bounds__(256, 3) void tail0_lse(
    const bf16* __restrict__ Ab, const bf16* __restrict__ W2b,
    float* __restrict__ ps) {
  __shared__ __align__(16) char As[128 * 128];
  __shared__ __align__(16) char Bs[128 * 128];
  __shared__ float reds[128];
  int tid = threadIdx.x;
  int lane = tid & 63, wave = tid >> 6;
  int wr = wave >> 1, wc = wave & 1;
  int tok0 = blockIdx.x * 128;
  int ys = blockIdx.y;
  int t_lo = (NT0 * ys) / JS0, t_hi = (NT0 * (ys + 1)) / JS0;
  float srun[4][4] = {};
  for (int jt = t_lo; jt < t_hi; ++jt) {
    int j0 = jt * 128;
    f32x4 acc[4][4] = {};
    for (int k0 = 0; k0 < H0S; k0 += 64) {
      __syncthreads();
      stage_tile(Ab, tok0, NTOK - 1, H0S, k0, As, wave, lane);
      stage_tile(W2b, j0, OSZ0 - 1, H0S, k0, Bs, wave, lane);
      __syncthreads();
#pragma unroll
      for (int kk = 0; kk < 2; ++kk) {
        short8v af[4], bfr[4];
#pragma unroll
        for (int m = 0; m < 4; ++m)
          af[m] = read_frag(As, wr * 64 + m * 16 + (lane & 15), kk, lane);
#pragma unroll
        for (int n = 0; n < 4; ++n)
          bfr[n] = read_frag(Bs, wc * 64 + n * 16 + (lane & 15), kk, lane);
#pragma unroll
        for (int m = 0; m < 4; ++m)
#pragma unroll
          for (int n = 0; n < 4; ++n)
            acc[m][n] = __builtin_amdgcn_mfma_f32_16x16x32_bf16(af[m], bfr[n], acc[m][n], 0, 0, 0);
      }
    }
#pragma unroll
    for (int m = 0; m < 4; ++m)
#pragma unroll
      for (int n = 0; n < 4; ++n) {
        int col = j0 + wc * 64 + n * 16 + (lane & 15);
        if (col < OSZ0) {
#pragma unroll
          for (int r = 0; r < 4; ++r) srun[m][r] += __expf(acc[m][n][r]);
        }
      }
  }
  reduce_write_ps(srun, reds, ps, ys, tok0, lane, wr, wc);
}

// ---------- tail1 (H=128): A-in-regs, dbuf B stream (R3-verified) ----------
__device__ void tail1_body(const bf16* __restrict__ Ab, const bf16* __restrict__ W2b,
                           float* __restrict__ ps, char* lds) {
  char* buf0 = lds;             // 32 KB
  char* buf1 = lds + 32768;     // 32 KB
  float* reds = (float*)(lds + 65536);
  int tid = threadIdx.x;
  int lane = tid & 63, wave = tid >> 6;
  int wr = wave >> 1, wc = wave & 1;
  int tok0 = blockIdx.x * 128;
  int ys = blockIdx.y;
  int t_lo = (NT1 * ys) / JS1, t_hi = (NT1 * (ys + 1)) / JS1;
  int nt = t_hi - t_lo;

  stage_tile256(Ab, tok0, NTOK - 1, H1S, buf1, wave, lane);
  WAIT_VM(0); SCHED_FENCE();
  RAW_BAR();
  short8v afr[4][4];
#pragma unroll
  for (int kk = 0; kk < 4; ++kk)
#pragma unroll
    for (int m = 0; m < 4; ++m)
      afr[kk][m] = read_frag256(buf1, wr * 64 + m * 16 + (lane & 15), kk, lane);
  stage_tile256(W2b, t_lo * 128, OSZ1 - 1, H1S, buf0, wave, lane);
  WAIT_LGKM0(); SCHED_FENCE();   // A-frag reads done before buf1 reuse
  RAW_BAR();
  if (nt > 1) stage_tile256(W2b, (t_lo + 1) * 128, OSZ1 - 1, H1S, buf1, wave, lane);

  float srun[4][4] = {};
  for (int i = 0; i < nt; ++i) {
    char* cur = (i & 1) ? buf1 : buf0;
    if (i + 1 < nt) { WAIT_VM(8); } else { WAIT_VM(0); }
    SCHED_FENCE();
    RAW_BAR();
    int j0 = (t_lo + i) * 128;
    f32x4 acc[4][4] = {};
#pragma unroll
    for (int kk = 0; kk < 4; ++kk) {
      short8v bfr[4];
#pragma unroll
      for (int n = 0; n < 4; ++n)
        bfr[n] = read_frag256(cur, wc * 64 + n * 16 + (lane & 15), kk, lane);
#pragma unroll
      for (int m = 0; m < 4; ++m)
#pragma unroll
        for (int n = 0; n < 4; ++n)
          acc[m][n] = __builtin_amdgcn_mfma_f32_16x16x32_bf16(afr[kk][m], bfr[n], acc[m][n], 0, 0, 0);
    }
#pragma unroll
    for (int m = 0; m < 4; ++m)
#pragma unroll
      for (int n = 0; n < 4; ++n) {
        int col = j0 + wc * 64 + n * 16 + (lane & 15);
        if (col < OSZ1) {
#pragma unroll
          for (int r = 0; r < 4; ++r) srun[m][r] += __expf(acc[m][n][r]);
        }
      }
    SCHED_FENCE();
    RAW_BAR();
    if (i + 2 < nt) stage_tile256(W2b, (t_lo + i + 2) * 128, OSZ1 - 1, H1S, cur, wave, lane);
  }
  reduce_write_ps(srun, reds, ps, ys, tok0, lane, wr, wc);
}

__global__ __launch_bounds__(256, 2) void tail1_lse(
    const bf16* __restrict__ Ab, const bf16* __restrict__ W2b,
    float* __restrict__ ps) {
  __shared__ __align__(16) char lds[66048];
  tail1_body(Ab, W2b, ps, lds);
}

// ---------- fused projection GEMM, dbuf counted-vmcnt (R5-verified) ----------
__device__ void proj_gemm_body(
    const bf16* __restrict__ A, const bf16* __restrict__ B,
    float* __restrict__ head, float* __restrict__ h0, bf16* __restrict__ h0b,
    float* __restrict__ h1, bf16* __restrict__ h1b, float* __restrict__ ps_head,
    char* lds) {
  char* Abuf[2] = {lds, lds + 16384};
  char* Bbuf[2] = {lds + 32768, lds + 49152};
  float* reds = (float*)(lds + 65536);
  int tid = threadIdx.x;
  int lane = tid & 63, wave = tid >> 6;
  int wr = wave >> 1, wc = wave & 1;
  int row0 = blockIdx.y * 128, col0 = blockIdx.x * 128;
  const int NIT = DIM / 64;  // 32
  stage_tile(A, row0, NTOK - 1, DIM, 0, Abuf[0], wave, lane);
  stage_tile(B, col0, NCAT - 1, DIM, 0, Bbuf[0], wave, lane);
  stage_tile(A, row0, NTOK - 1, DIM, 64, Abuf[1], wave, lane);
  stage_tile(B, col0, NCAT - 1, DIM, 64, Bbuf[1], wave, lane);
  f32x4 acc[4][4] = {};
  for (int it = 0; it < NIT; ++it) {
    char* Ac = Abuf[it & 1];
    char* Bc = Bbuf[it & 1];
    if (it + 1 < NIT) { WAIT_VM(8); } else { WAIT_VM(0); }
    SCHED_FENCE();
    RAW_BAR();
#pragma unroll
    for (int kk = 0; kk < 2; ++kk) {
      short8v af[4], bfr[4];
#pragma unroll
      for (int m = 0; m < 4; ++m)
        af[m] = read_frag(Ac, wr * 64 + m * 16 + (lane & 15), kk, lane);
#pragma unroll
      for (int n = 0; n < 4; ++n)
        bfr[n] = read_frag(Bc, wc * 64 + n * 16 + (lane & 15), kk, lane);
#pragma unroll
      for (int m = 0; m < 4; ++m)
#pragma unroll
        for (int n = 0; n < 4; ++n)
          acc[m][n] = __builtin_amdgcn_mfma_f32_16x16x32_bf16(af[m], bfr[n], acc[m][n], 0, 0, 0);
    }
    SCHED_FENCE();
    RAW_BAR();
    if (it + 2 < NIT) {
      stage_tile(A, row0, NTOK - 1, DIM, (it + 2) * 64, Ac, wave, lane);
      stage_tile(B, col0, NCAT - 1, DIM, (it + 2) * 64, Bc, wave, lane);
    }
  }
  float srun[4][4] = {};
#pragma unroll
  for (int m = 0; m < 4; ++m) {
    int row = row0 + wr * 64 + m * 16 + (lane >> 4) * 4;
#pragma unroll
    for (int n = 0; n < 4; ++n) {
      int col = col0 + wc * 64 + n * 16 + (lane & 15);
#pragma unroll
      for (int r = 0; r < 4; ++r) {
        float v = acc[m][n][r];
        if (col < NHEAD) {
          head[(size_t)(row + r) * NHEAD + col] = v;
          srun[m][r] += __expf(v);
        } else if (col >= 1024 && col < 1536) {
          h0[(size_t)(row + r) * H0S + (col - 1024)] = v;
          h0b[(size_t)(row + r) * H0S + (col - 1024)] = __float2bfloat16(v);
        } else if (col >= 1536) {
          h1[(size_t)(row + r) * H1S + (col - 1536)] = v;
          h1b[(size_t)(row + r) * H1S + (col - 1536)] = __float2bfloat16(v);
        }
      }
    }
  }
  if (blockIdx.x < HEADBLKS) {
    reduce_write_ps(srun, reds, ps_head, blockIdx.x, row0, lane, wr, wc);
  }
}

__global__ __launch_bounds__(256, 2) void proj_gemm(
    const bf16* __restrict__ A, const bf16* __restrict__ B,
    float* __restrict__ head, float* __restrict__ h0, bf16* __restrict__ h0b,
    float* __restrict__ h1, bf16* __restrict__ h1b, float* __restrict__ ps_head) {
  __shared__ __align__(16) char lds[66048];
  proj_gemm_body(A, B, head, h0, h0b, h1, h1b, ps_head, lds);
}

// ---------- finalize: one wave per token ----------
__global__ __launch_bounds__(256) void finalize2(
    const int* __restrict__ target, const float* __restrict__ head,
    const float* __restrict__ ps_head,
    const float* __restrict__ h0, const float* __restrict__ h1,
    const float* __restrict__ W2_0, const float* __restrict__ W2_1,
    const float* __restrict__ ps0, const float* __restrict__ ps1,
    float* __restrict__ out) {
  int warp = threadIdx.x >> 6, lane = threadIdx.x & 63;
  int i = blockIdx.x * 4 + warp;
  if (i >= NTOK) return;
  int t = target[i];
  float sh = 0.f;
#pragma unroll
  for (int s = 0; s < HEADBLKS; ++s) sh += ps_head[(size_t)s * NTOK + i];
  float lse_head = logf(sh);
  float res;
  if (t < C0LO) {
    res = head[(size_t)i * NHEAD + t] - lse_head;
  } else {
    int c = (t < C0HI) ? 0 : 1;
    int H = c ? H1S : H0S;
    int low = c ? C0HI : C0LO;
    const float* hv = (c ? h1 : h0) + (size_t)i * H;
    const float* wv = (c ? W2_1 : W2_0) + (size_t)(t - low) * H;
    float p = 0.f;
    for (int k = lane * 4; k < H; k += 256) {
      float4 a = *reinterpret_cast<const float4*>(hv + k);
      float4 b = *reinterpret_cast<const float4*>(wv + k);
      p += a.x * b.x + a.y * b.y + a.z * b.z + a.w * b.w;
    }
#pragma unroll
    for (int off = 32; off > 0; off >>= 1) p += __shfl_xor(p, off);
    const float* ps = c ? ps1 : ps0;
    int js = c ? JS1 : JS0;   // per-cluster slice count (JS0 != JS1)
    float S = 0.f;
    for (int s = 0; s < js; ++s) S += ps[(size_t)s * NTOK + i];
    float cl = head[(size_t)i * NHEAD + C0LO + c];
    res = (cl - lse_head) + (p - logf(S));
  }
  if (lane == 0) out[i] = res;
}

__global__ __launch_bounds__(256) void loss_kernel(float* __restrict__ out) {
  __shared__ float red[256];
  int tid = threadIdx.x;
  float s = 0.f;
  for (int j = tid; j < NTOK; j += 256) s += out[j];
  red[tid] = s; __syncthreads();
  for (int off = 128; off > 0; off >>= 1) {
    if (tid < off) red[tid] += red[tid + off];
    __syncthreads();
  }
  if (tid == 0) out[NTOK] = -red[0] / (float)NTOK;
}

extern "C" void kernel_launch(void* const* d_in, const int* in_sizes, int n_in,
                              void* d_out, int out_size, void* d_ws, size_t ws_size,
                              hipStream_t stream) {
  (void)in_sizes; (void)n_in; (void)out_size; (void)ws_size;
  const float* x = (const float*)d_in[0];
  const int* target = (const int*)d_in[1];
  const float* W_head = (const float*)d_in[2];
  const float* W1_0 = (const float*)d_in[3];
  const float* W2_0 = (const float*)d_in[4];
  const float* W1_1 = (const float*)d_in[5];
  const float* W2_1 = (const float*)d_in[6];
  float* out = (float*)d_out;

  char* w = (char*)d_ws;
  size_t off = 0;
  auto alloc = [&](size_t bytes) -> void* {
    void* p = w + off;
    off = (off + bytes + 255) & ~(size_t)255;
    return p;
  };
  bf16* xb   = (bf16*)alloc((size_t)NTOK * DIM * 2);
  bf16* Wcat = (bf16*)alloc((size_t)NCAT * DIM * 2);
  bf16* W20b = (bf16*)alloc((size_t)OSZ0 * H0S * 2);
  bf16* W21b = (bf16*)alloc((size_t)OSZ1 * H1S * 2);
  float* head = (float*)alloc((size_t)NTOK * NHEAD * 4);
  float* h0   = (float*)alloc((size_t)NTOK * H0S * 4);
  bf16*  h0b  = (bf16*)alloc((size_t)NTOK * H0S * 2);
  float* h1   = (float*)alloc((size_t)NTOK * H1S * 4);
  bf16*  h1b  = (bf16*)alloc((size_t)NTOK * H1S * 2);
  float* ps_head = (float*)alloc((size_t)HEADBLKS * NTOK * 4);
  float* ps0 = (float*)alloc((size_t)JS0 * NTOK * 4);
  float* ps1 = (float*)alloc((size_t)JS1 * NTOK * 4);

  dim3 blk(256);
  const long TOT8 = (long)NTOK * DIM / 8 + (long)NCAT * DIM / 8 +
                    (long)OSZ0 * H0S / 8 + (long)OSZ1 * H1S / 8;
  cvt_all<<<dim3((unsigned)((TOT8 + 255) / 256)), blk, 0, stream>>>(
      x, W_head, W1_0, W1_1, W2_0, W2_1, xb, Wcat, W20b, W21b);

  proj_gemm<<<dim3(NCAT / 128, NTOK / 128), blk, 0, stream>>>(
      xb, Wcat, head, h0, h0b, h1, h1b, ps_head);

  tail0_lse<<<dim3(NTOK / 128, JS0), blk, 0, stream>>>(h0b, W20b, ps0);
  tail1_lse<<<dim3(NTOK / 128, JS1), blk, 0, stream>>>(h1b, W21b, ps1);

  finalize2<<<dim3(NTOK / 4), blk, 0, stream>>>(target, head, ps_head, h0, h1,
                                                W2_0, W2_1, ps0, ps1, out);
  loss_kernel<<<1, blk, 0, stream>>>(out);
}

// Round 8
// 208.252 us; speedup vs baseline: 1.3082x; 1.1513x over previous
//
#include <hip/hip_runtime.h>
#include <hip/hip_bf16.h>
#include <math.h>

#define NTOK 4096
#define DIM 2048
#define NHEAD 1002
#define NCAT 1664
#define C0LO 1000
#define C0HI 10000
#define OSZ0 9000
#define OSZ1 40257
#define H0S 512
#define H1S 128
#define JS0 24               // tail0 j-slices: 768 blocks -> 3 blocks/CU @ 33KB LDS, (256,3)
#define JS1 16               // tail1 j-slices (512 blocks, 66KB LDS -> 2 blocks/CU)
#define HEADBLKS 8
#define NT0 71               // ceil(9000/128)
#define NT1 315              // ceil(40257/128)

typedef __attribute__((ext_vector_type(4))) short short4v;
typedef __attribute__((ext_vector_type(8))) short short8v;
typedef __attribute__((ext_vector_type(4))) float f32x4;
typedef __hip_bfloat16 bf16;

#define GLOBAL_AS __attribute__((address_space(1)))
#define LDS_AS __attribute__((address_space(3)))

#define RAW_BAR() __builtin_amdgcn_s_barrier()
#define SCHED_FENCE() __builtin_amdgcn_sched_barrier(0)
#define WAIT_VM(N) asm volatile("s_waitcnt vmcnt(" #N ")" ::: "memory")
#define WAIT_LGKM0() asm volatile("s_waitcnt lgkmcnt(0)" ::: "memory")

// ---------- fused fp32->bf16 convert + Wcat concat ----------
__global__ __launch_bounds__(256) void cvt_all(
    const float* __restrict__ x, const float* __restrict__ W_head,
    const float* __restrict__ W1_0, const float* __restrict__ W1_1,
    const float* __restrict__ W2_0, const float* __restrict__ W2_1,
    bf16* __restrict__ xb, bf16* __restrict__ Wcat,
    bf16* __restrict__ W20b, bf16* __restrict__ W21b) {
  const long NX = (long)NTOK * DIM / 8;
  const long NC = (long)NCAT * DIM / 8;
  const long N20 = (long)OSZ0 * H0S / 8;
  const long N21 = (long)OSZ1 * H1S / 8;
  long gid = (long)blockIdx.x * 256 + threadIdx.x;
  const float* src = nullptr;
  bf16* dst;
  if (gid < NX) {
    src = x + gid * 8; dst = xb + gid * 8;
  } else if (gid < NX + NC) {
    long o = (gid - NX) * 8;
    int row = (int)(o >> 11), k = (int)(o & 2047);
    dst = Wcat + o;
    if (row < NHEAD) src = W_head + (long)row * DIM + k;
    else if (row < 1024) src = nullptr;              // zero padding rows
    else if (row < 1536) src = W1_0 + (long)(row - 1024) * DIM + k;
    else src = W1_1 + (long)(row - 1536) * DIM + k;
  } else if (gid < NX + NC + N20) {
    long o = (gid - NX - NC) * 8; src = W2_0 + o; dst = W20b + o;
  } else if (gid < NX + NC + N20 + N21) {
    long o = (gid - NX - NC - N20) * 8; src = W2_1 + o; dst = W21b + o;
  } else {
    return;
  }
  union { short8v v; bf16 h[8]; } u;
  if (src) {
    float4 a = *reinterpret_cast<const float4*>(src);
    float4 b = *reinterpret_cast<const float4*>(src + 4);
    u.h[0] = __float2bfloat16(a.x); u.h[1] = __float2bfloat16(a.y);
    u.h[2] = __float2bfloat16(a.z); u.h[3] = __float2bfloat16(a.w);
    u.h[4] = __float2bfloat16(b.x); u.h[5] = __float2bfloat16(b.y);
    u.h[6] = __float2bfloat16(b.z); u.h[7] = __float2bfloat16(b.w);
  } else {
#pragma unroll
    for (int e = 0; e < 8; ++e) u.h[e] = __float2bfloat16(0.f);
  }
  *reinterpret_cast<short8v*>(dst) = u.v;
}

// ---------- 128B-row staging (BK=64 slice), verified R2/R3 ----------
__device__ __forceinline__ void stage_tile(const bf16* __restrict__ g, int row0,
                                           int maxrow, int ld, int k0,
                                           char* lds, int wave, int lane) {
#pragma unroll
  for (int c = 0; c < 4; ++c) {
    int rbase = wave * 32 + c * 8;
    int row = rbase + (lane >> 3);
    int grow = row0 + row;
    grow = grow < maxrow ? grow : maxrow;
    int slot = (lane & 7) ^ (row & 7);
    const bf16* src = g + (size_t)grow * ld + k0 + slot * 8;
    __builtin_amdgcn_global_load_lds((const GLOBAL_AS unsigned int*)src,
                                     (LDS_AS unsigned int*)(lds + rbase * 128),
                                     16, 0, 0);
  }
}

__device__ __forceinline__ short8v read_frag(const char* lds, int row, int kk, int lane) {
  int g = lane >> 4;
  int r7 = row & 7;
  int b1 = kk * 64 + g * 8;
  int b2 = b1 + 32;
  b1 = ((b1 >> 4) ^ r7) * 16 + (b1 & 15);
  b2 = ((b2 >> 4) ^ r7) * 16 + (b2 & 15);
  const char* p = lds + row * 128;
  short4v lo = *reinterpret_cast<const short4v*>(p + b1);
  short4v hi = *reinterpret_cast<const short4v*>(p + b2);
  return __builtin_shufflevector(lo, hi, 0, 1, 2, 3, 4, 5, 6, 7);
}

// ---------- 256B-row staging (whole K=128 tile, tail1) ----------
__device__ __forceinline__ void stage_tile256(const bf16* __restrict__ g, int row0,
                                              int maxrow, int ld,
                                              char* lds, int wave, int lane) {
#pragma unroll
  for (int c = 0; c < 8; ++c) {
    int rbase = wave * 32 + c * 4;
    int row = rbase + (lane >> 4);
    int grow = row0 + row;
    grow = grow < maxrow ? grow : maxrow;
    int slot = (lane & 15) ^ (row & 7);
    const bf16* src = g + (size_t)grow * ld + slot * 8;
    __builtin_amdgcn_global_load_lds((const GLOBAL_AS unsigned int*)src,
                                     (LDS_AS unsigned int*)(lds + rbase * 256),
                                     16, 0, 0);
  }
}

__device__ __forceinline__ short8v read_frag256(const char* lds, int row, int kk, int lane) {
  int g = lane >> 4;
  int r7 = row & 7;
  int b1 = kk * 64 + g * 8;
  int b2 = b1 + 32;
  b1 = (((b1 >> 4) ^ r7) << 4) | (b1 & 15);
  b2 = (((b2 >> 4) ^ r7) << 4) | (b2 & 15);
  const char* p = lds + row * 256;
  short4v lo = *reinterpret_cast<const short4v*>(p + b1);
  short4v hi = *reinterpret_cast<const short4v*>(p + b2);
  return __builtin_shufflevector(lo, hi, 0, 1, 2, 3, 4, 5, 6, 7);
}

// shared sum-exp tree reduce + partial-sum write (layout identical R2/R3)
__device__ __forceinline__ void reduce_write_ps(float srun[4][4], float* reds,
                                                float* ps, int slice, int tok0,
                                                int lane, int wr, int wc) {
#pragma unroll
  for (int off = 1; off < 16; off <<= 1)
#pragma unroll
    for (int m = 0; m < 4; ++m)
#pragma unroll
      for (int r = 0; r < 4; ++r) srun[m][r] += __shfl_xor(srun[m][r], off);
  __syncthreads();
  if (wc == 0 && (lane & 15) == 0) {
#pragma unroll
    for (int m = 0; m < 4; ++m)
#pragma unroll
      for (int r = 0; r < 4; ++r)
        reds[wr * 64 + m * 16 + (lane >> 4) * 4 + r] = srun[m][r];
  }
  __syncthreads();
  if (wc == 1 && (lane & 15) == 0) {
#pragma unroll
    for (int m = 0; m < 4; ++m)
#pragma unroll
      for (int r = 0; r < 4; ++r) {
        int row = wr * 64 + m * 16 + (lane >> 4) * 4 + r;
        ps[(size_t)slice * NTOK + tok0 + row] = reds[row] + srun[m][r];
      }
  }
}

// ---------- tail0 (H=512): R3-verified 2-barrier structure, 33KB LDS ----------
// (256,3): unified reg budget 170/wave >= 152 needed. (256,4)=128 spilled (R6).
// 1D grid 768 = 8 XCD-chunks x 96; each XCD owns 4 tok-panels (A L2-resident).
__global__ __launch_bounds__(256, 3) void tail0_lse(
    const bf16* __restrict__ Ab, const bf16* __restrict__ W2b,
    float* __restrict__ ps) {
  __shared__ __align__(16) char As[128 * 128];
  __shared__ __align__(16) char Bs[128 * 128];
  __shared__ float reds[128];
  int tid = threadIdx.x;
  int lane = tid & 63, wave = tid >> 6;
  int wr = wave >> 1, wc = wave & 1;
  int wgid = blockIdx.x;
  int cx = wgid & 7, w = wgid >> 3;    // 768 = 8 * 96
  int tb = cx * 4 + (w & 3);           // 0..31 tok-block
  int ys = w >> 2;                     // 0..23 j-slice
  int tok0 = tb * 128;
  int t_lo = (NT0 * ys) / JS0, t_hi = (NT0 * (ys + 1)) / JS0;
  float srun[4][4] = {};
  for (int jt = t_lo; jt < t_hi; ++jt) {
    int j0 = jt * 128;
    f32x4 acc[4][4] = {};
    for (int k0 = 0; k0 < H0S; k0 += 64) {
      __syncthreads();
      stage_tile(Ab, tok0, NTOK - 1, H0S, k0, As, wave, lane);
      stage_tile(W2b, j0, OSZ0 - 1, H0S, k0, Bs, wave, lane);
      __syncthreads();
#pragma unroll
      for (int kk = 0; kk < 2; ++kk) {
        short8v af[4], bfr[4];
#pragma unroll
        for (int m = 0; m < 4; ++m)
          af[m] = read_frag(As, wr * 64 + m * 16 + (lane & 15), kk, lane);
#pragma unroll
        for (int n = 0; n < 4; ++n)
          bfr[n] = read_frag(Bs, wc * 64 + n * 16 + (lane & 15), kk, lane);
#pragma unroll
        for (int m = 0; m < 4; ++m)
#pragma unroll
          for (int n = 0; n < 4; ++n)
            acc[m][n] = __builtin_amdgcn_mfma_f32_16x16x32_bf16(af[m], bfr[n], acc[m][n], 0, 0, 0);
      }
    }
#pragma unroll
    for (int m = 0; m < 4; ++m)
#pragma unroll
      for (int n = 0; n < 4; ++n) {
        int col = j0 + wc * 64 + n * 16 + (lane & 15);
        if (col < OSZ0) {
#pragma unroll
          for (int r = 0; r < 4; ++r) srun[m][r] += __expf(acc[m][n][r]);
        }
      }
  }
  reduce_write_ps(srun, reds, ps, ys, tok0, lane, wr, wc);
}

// ---------- tail1 (H=128): A-in-regs, dbuf B stream (R3-verified) ----------
__device__ void tail1_body(const bf16* __restrict__ Ab, const bf16* __restrict__ W2b,
                           float* __restrict__ ps, char* lds) {
  char* buf0 = lds;             // 32 KB
  char* buf1 = lds + 32768;     // 32 KB
  float* reds = (float*)(lds + 65536);
  int tid = threadIdx.x;
  int lane = tid & 63, wave = tid >> 6;
  int wr = wave >> 1, wc = wave & 1;
  int wgid = blockIdx.x;
  int cx = wgid & 7, w = wgid >> 3;    // 512 = 8 * 64
  int tb = cx * 4 + (w & 3);           // 0..31
  int ys = w >> 2;                     // 0..15
  int tok0 = tb * 128;
  int t_lo = (NT1 * ys) / JS1, t_hi = (NT1 * (ys + 1)) / JS1;
  int nt = t_hi - t_lo;

  stage_tile256(Ab, tok0, NTOK - 1, H1S, buf1, wave, lane);
  WAIT_VM(0); SCHED_FENCE();
  RAW_BAR();
  short8v afr[4][4];
#pragma unroll
  for (int kk = 0; kk < 4; ++kk)
#pragma unroll
    for (int m = 0; m < 4; ++m)
      afr[kk][m] = read_frag256(buf1, wr * 64 + m * 16 + (lane & 15), kk, lane);
  stage_tile256(W2b, t_lo * 128, OSZ1 - 1, H1S, buf0, wave, lane);
  WAIT_LGKM0(); SCHED_FENCE();   // A-frag reads done before buf1 reuse
  RAW_BAR();
  if (nt > 1) stage_tile256(W2b, (t_lo + 1) * 128, OSZ1 - 1, H1S, buf1, wave, lane);

  float srun[4][4] = {};
  for (int i = 0; i < nt; ++i) {
    char* cur = (i & 1) ? buf1 : buf0;
    if (i + 1 < nt) { WAIT_VM(8); } else { WAIT_VM(0); }
    SCHED_FENCE();
    RAW_BAR();
    int j0 = (t_lo + i) * 128;
    f32x4 acc[4][4] = {};
#pragma unroll
    for (int kk = 0; kk < 4; ++kk) {
      short8v bfr[4];
#pragma unroll
      for (int n = 0; n < 4; ++n)
        bfr[n] = read_frag256(cur, wc * 64 + n * 16 + (lane & 15), kk, lane);
#pragma unroll
      for (int m = 0; m < 4; ++m)
#pragma unroll
        for (int n = 0; n < 4; ++n)
          acc[m][n] = __builtin_amdgcn_mfma_f32_16x16x32_bf16(afr[kk][m], bfr[n], acc[m][n], 0, 0, 0);
    }
#pragma unroll
    for (int m = 0; m < 4; ++m)
#pragma unroll
      for (int n = 0; n < 4; ++n) {
        int col = j0 + wc * 64 + n * 16 + (lane & 15);
        if (col < OSZ1) {
#pragma unroll
          for (int r = 0; r < 4; ++r) srun[m][r] += __expf(acc[m][n][r]);
        }
      }
    SCHED_FENCE();
    RAW_BAR();
    if (i + 2 < nt) stage_tile256(W2b, (t_lo + i + 2) * 128, OSZ1 - 1, H1S, cur, wave, lane);
  }
  reduce_write_ps(srun, reds, ps, ys, tok0, lane, wr, wc);
}

__global__ __launch_bounds__(256, 2) void tail1_lse(
    const bf16* __restrict__ Ab, const bf16* __restrict__ W2b,
    float* __restrict__ ps) {
  __shared__ __align__(16) char lds[66048];
  tail1_body(Ab, W2b, ps, lds);
}

// ---------- fused projection GEMM: R3 2-barrier structure, 33KB LDS ----------
// Piped 66KB version measured 89us @ MfmaUtil 12% (R7) - REGRESSION, reverted.
// 1D grid 416 = 8 XCD-chunks x 52 (13 col x 4 row); A panels L2-resident/XCD.
__global__ __launch_bounds__(256, 3) void proj_gemm(
    const bf16* __restrict__ A, const bf16* __restrict__ B,
    float* __restrict__ head, float* __restrict__ h0, bf16* __restrict__ h0b,
    float* __restrict__ h1, bf16* __restrict__ h1b, float* __restrict__ ps_head) {
  __shared__ __align__(16) char As[16384];
  __shared__ __align__(16) char Bs[16384];
  __shared__ float reds[128];
  int tid = threadIdx.x;
  int lane = tid & 63, wave = tid >> 6;
  int wr = wave >> 1, wc = wave & 1;
  int wgid = blockIdx.x;
  int cx = wgid & 7, w = wgid >> 3;    // 416 = 8 * 52
  int col_b = w >> 2;                  // 0..12
  int row_b = cx * 4 + (w & 3);        // 0..31
  int row0 = row_b * 128, col0 = col_b * 128;
  f32x4 acc[4][4] = {};
  for (int k0 = 0; k0 < DIM; k0 += 64) {
    __syncthreads();
    stage_tile(A, row0, NTOK - 1, DIM, k0, As, wave, lane);
    stage_tile(B, col0, NCAT - 1, DIM, k0, Bs, wave, lane);
    __syncthreads();
#pragma unroll
    for (int kk = 0; kk < 2; ++kk) {
      short8v af[4], bfr[4];
#pragma unroll
      for (int m = 0; m < 4; ++m)
        af[m] = read_frag(As, wr * 64 + m * 16 + (lane & 15), kk, lane);
#pragma unroll
      for (int n = 0; n < 4; ++n)
        bfr[n] = read_frag(Bs, wc * 64 + n * 16 + (lane & 15), kk, lane);
#pragma unroll
      for (int m = 0; m < 4; ++m)
#pragma unroll
        for (int n = 0; n < 4; ++n)
          acc[m][n] = __builtin_amdgcn_mfma_f32_16x16x32_bf16(af[m], bfr[n], acc[m][n], 0, 0, 0);
    }
  }
  float srun[4][4] = {};
#pragma unroll
  for (int m = 0; m < 4; ++m) {
    int row = row0 + wr * 64 + m * 16 + (lane >> 4) * 4;
#pragma unroll
    for (int n = 0; n < 4; ++n) {
      int col = col0 + wc * 64 + n * 16 + (lane & 15);
#pragma unroll
      for (int r = 0; r < 4; ++r) {
        float v = acc[m][n][r];
        if (col < NHEAD) {
          head[(size_t)(row + r) * NHEAD + col] = v;
          srun[m][r] += __expf(v);
        } else if (col >= 1024 && col < 1536) {
          h0[(size_t)(row + r) * H0S + (col - 1024)] = v;
          h0b[(size_t)(row + r) * H0S + (col - 1024)] = __float2bfloat16(v);
        } else if (col >= 1536) {
          h1[(size_t)(row + r) * H1S + (col - 1536)] = v;
          h1b[(size_t)(row + r) * H1S + (col - 1536)] = __float2bfloat16(v);
        }
      }
    }
  }
  if (col_b < HEADBLKS) {
    reduce_write_ps(srun, reds, ps_head, col_b, row0, lane, wr, wc);
  }
}

// ---------- finalize: one wave per token ----------
__global__ __launch_bounds__(256) void finalize2(
    const int* __restrict__ target, const float* __restrict__ head,
    const float* __restrict__ ps_head,
    const float* __restrict__ h0, const float* __restrict__ h1,
    const float* __restrict__ W2_0, const float* __restrict__ W2_1,
    const float* __restrict__ ps0, const float* __restrict__ ps1,
    float* __restrict__ out) {
  int warp = threadIdx.x >> 6, lane = threadIdx.x & 63;
  int i = blockIdx.x * 4 + warp;
  if (i >= NTOK) return;
  int t = target[i];
  float sh = 0.f;
#pragma unroll
  for (int s = 0; s < HEADBLKS; ++s) sh += ps_head[(size_t)s * NTOK + i];
  float lse_head = logf(sh);
  float res;
  if (t < C0LO) {
    res = head[(size_t)i * NHEAD + t] - lse_head;
  } else {
    int c = (t < C0HI) ? 0 : 1;
    int H = c ? H1S : H0S;
    int low = c ? C0HI : C0LO;
    const float* hv = (c ? h1 : h0) + (size_t)i * H;
    const float* wv = (c ? W2_1 : W2_0) + (size_t)(t - low) * H;
    float p = 0.f;
    for (int k = lane * 4; k < H; k += 256) {
      float4 a = *reinterpret_cast<const float4*>(hv + k);
      float4 b = *reinterpret_cast<const float4*>(wv + k);
      p += a.x * b.x + a.y * b.y + a.z * b.z + a.w * b.w;
    }
#pragma unroll
    for (int off = 32; off > 0; off >>= 1) p += __shfl_xor(p, off);
    const float* ps = c ? ps1 : ps0;
    int js = c ? JS1 : JS0;   // per-cluster slice count (JS0 != JS1)
    float S = 0.f;
    for (int s = 0; s < js; ++s) S += ps[(size_t)s * NTOK + i];
    float cl = head[(size_t)i * NHEAD + C0LO + c];
    res = (cl - lse_head) + (p - logf(S));
  }
  if (lane == 0) out[i] = res;
}

__global__ __launch_bounds__(256) void loss_kernel(float* __restrict__ out) {
  __shared__ float red[256];
  int tid = threadIdx.x;
  float s = 0.f;
  for (int j = tid; j < NTOK; j += 256) s += out[j];
  red[tid] = s; __syncthreads();
  for (int off = 128; off > 0; off >>= 1) {
    if (tid < off) red[tid] += red[tid + off];
    __syncthreads();
  }
  if (tid == 0) out[NTOK] = -red[0] / (float)NTOK;
}

extern "C" void kernel_launch(void* const* d_in, const int* in_sizes, int n_in,
                              void* d_out, int out_size, void* d_ws, size_t ws_size,
                              hipStream_t stream) {
  (void)in_sizes; (void)n_in; (void)out_size; (void)ws_size;
  const float* x = (const float*)d_in[0];
  const int* target = (const int*)d_in[1];
  const float* W_head = (const float*)d_in[2];
  const float* W1_0 = (const float*)d_in[3];
  const float* W2_0 = (const float*)d_in[4];
  const float* W1_1 = (const float*)d_in[5];
  const float* W2_1 = (const float*)d_in[6];
  float* out = (float*)d_out;

  char* w = (char*)d_ws;
  size_t off = 0;
  auto alloc = [&](size_t bytes) -> void* {
    void* p = w + off;
    off = (off + bytes + 255) & ~(size_t)255;
    return p;
  };
  bf16* xb   = (bf16*)alloc((size_t)NTOK * DIM * 2);
  bf16* Wcat = (bf16*)alloc((size_t)NCAT * DIM * 2);
  bf16* W20b = (bf16*)alloc((size_t)OSZ0 * H0S * 2);
  bf16* W21b = (bf16*)alloc((size_t)OSZ1 * H1S * 2);
  float* head = (float*)alloc((size_t)NTOK * NHEAD * 4);
  float* h0   = (float*)alloc((size_t)NTOK * H0S * 4);
  bf16*  h0b  = (bf16*)alloc((size_t)NTOK * H0S * 2);
  float* h1   = (float*)alloc((size_t)NTOK * H1S * 4);
  bf16*  h1b  = (bf16*)alloc((size_t)NTOK * H1S * 2);
  float* ps_head = (float*)alloc((size_t)HEADBLKS * NTOK * 4);
  float* ps0 = (float*)alloc((size_t)JS0 * NTOK * 4);
  float* ps1 = (float*)alloc((size_t)JS1 * NTOK * 4);

  dim3 blk(256);
  const long TOT8 = (long)NTOK * DIM / 8 + (long)NCAT * DIM / 8 +
                    (long)OSZ0 * H0S / 8 + (long)OSZ1 * H1S / 8;
  cvt_all<<<dim3((unsigned)((TOT8 + 255) / 256)), blk, 0, stream>>>(
      x, W_head, W1_0, W1_1, W2_0, W2_1, xb, Wcat, W20b, W21b);

  proj_gemm<<<dim3(416), blk, 0, stream>>>(
      xb, Wcat, head, h0, h0b, h1, h1b, ps_head);

  tail0_lse<<<dim3(32 * JS0), blk, 0, stream>>>(h0b, W20b, ps0);
  tail1_lse<<<dim3(32 * JS1), blk, 0, stream>>>(h1b, W21b, ps1);

  finalize2<<<dim3(NTOK / 4), blk, 0, stream>>>(target, head, ps_head, h0, h1,
                                                W2_0, W2_1, ps0, ps1, out);
  loss_kernel<<<1, blk, 0, stream>>>(out);
}

// Round 9
// 184.469 us; speedup vs baseline: 1.4769x; 1.1289x over previous
//
#include <hip/hip_runtime.h>
#include <hip/hip_bf16.h>
#include <math.h>

#define NTOK 4096
#define DIM 2048
#define NHEAD 1002
#define NCAT 1664
#define C0LO 1000
#define C0HI 10000
#define OSZ0 9000
#define OSZ1 40257
#define H0S 512
#define H1S 128
#define JS0 24               // tail0: 768 blocks, 3/CU @ 33KB LDS, (256,3) [R7: 64us]
#define JS1 16               // tail1: 512 blocks, 66KB LDS, 2/CU
#define HEADBLKS 8
#define NT0 71               // ceil(9000/128)
#define NT1 315              // ceil(40257/128)

typedef __attribute__((ext_vector_type(4))) short short4v;
typedef __attribute__((ext_vector_type(8))) short short8v;
typedef __attribute__((ext_vector_type(4))) float f32x4;
typedef __hip_bfloat16 bf16;

#define GLOBAL_AS __attribute__((address_space(1)))
#define LDS_AS __attribute__((address_space(3)))

#define RAW_BAR() __builtin_amdgcn_s_barrier()
#define SCHED_FENCE() __builtin_amdgcn_sched_barrier(0)
#define WAIT_VM(N) asm volatile("s_waitcnt vmcnt(" #N ")" ::: "memory")
#define WAIT_LGKM0() asm volatile("s_waitcnt lgkmcnt(0)" ::: "memory")

// k-interleave permutation within each 32-elem chunk: frag elems contiguous.
// pos(k) = g*8 + h*4 + e  where g=(k&15)>>2, h=(k>>4)&1, e=k&3.
__device__ __forceinline__ int kperm(int c) {
  return (c & ~31) | (((c & 15) >> 2) << 3) | (((c >> 4) & 1) << 2) | (c & 3);
}

// ---------- fused fp32->bf16 convert + concat, k-INTERLEAVED output ----------
// Each thread emits 8 contiguous bf16 at out pos [8g..8g+7] of a 32-chunk,
// gathered from source k = chunk+4g+0..3 and chunk+4g+16..19 (two float4s).
__global__ __launch_bounds__(256) void cvt_all(
    const float* __restrict__ x, const float* __restrict__ W_head,
    const float* __restrict__ W1_0, const float* __restrict__ W1_1,
    const float* __restrict__ W2_0, const float* __restrict__ W2_1,
    bf16* __restrict__ xb, bf16* __restrict__ Wcat,
    bf16* __restrict__ W20b, bf16* __restrict__ W21b) {
  const long NX = (long)NTOK * DIM / 8;
  const long NC = (long)NCAT * DIM / 8;
  const long N20 = (long)OSZ0 * H0S / 8;
  const long N21 = (long)OSZ1 * H1S / 8;
  long gid = (long)blockIdx.x * 256 + threadIdx.x;
  const float* s1 = nullptr;   // 4 fp32 @ chunk+4g
  const float* s2 = nullptr;   // 4 fp32 @ chunk+4g+16
  bf16* dst;
  long rel;
  if (gid < NX) {
    rel = gid * 8;
    long c1 = (rel & ~31L) + ((rel >> 3) & 3) * 4;
    s1 = x + c1; s2 = x + c1 + 16;
    dst = xb + rel;
  } else if (gid < NX + NC) {
    rel = (gid - NX) * 8;
    int row = (int)(rel >> 11);
    long c1 = (rel & ~31L) + ((rel >> 3) & 3) * 4;
    int col = (int)(c1 & 2047);
    dst = Wcat + rel;
    const float* srow = nullptr;
    if (row < NHEAD) srow = W_head + (long)row * DIM;
    else if (row < 1024) srow = nullptr;             // zero padding rows
    else if (row < 1536) srow = W1_0 + (long)(row - 1024) * DIM;
    else srow = W1_1 + (long)(row - 1536) * DIM;
    if (srow) { s1 = srow + col; s2 = srow + col + 16; }
  } else if (gid < NX + NC + N20) {
    rel = (gid - NX - NC) * 8;
    long c1 = (rel & ~31L) + ((rel >> 3) & 3) * 4;
    s1 = W2_0 + c1; s2 = W2_0 + c1 + 16;
    dst = W20b + rel;
  } else if (gid < NX + NC + N20 + N21) {
    rel = (gid - NX - NC - N20) * 8;
    long c1 = (rel & ~31L) + ((rel >> 3) & 3) * 4;
    s1 = W2_1 + c1; s2 = W2_1 + c1 + 16;
    dst = W21b + rel;
  } else {
    return;
  }
  union { short8v v; bf16 h[8]; } u;
  if (s1) {
    float4 a = *reinterpret_cast<const float4*>(s1);
    float4 b = *reinterpret_cast<const float4*>(s2);
    u.h[0] = __float2bfloat16(a.x); u.h[1] = __float2bfloat16(a.y);
    u.h[2] = __float2bfloat16(a.z); u.h[3] = __float2bfloat16(a.w);
    u.h[4] = __float2bfloat16(b.x); u.h[5] = __float2bfloat16(b.y);
    u.h[6] = __float2bfloat16(b.z); u.h[7] = __float2bfloat16(b.w);
  } else {
#pragma unroll
    for (int e = 0; e < 8; ++e) u.h[e] = __float2bfloat16(0.f);
  }
  *reinterpret_cast<short8v*>(dst) = u.v;
}

// ---------- 128B-row staging (BK=64), 16B-slot XOR swizzle on source ----------
__device__ __forceinline__ void stage_tile(const bf16* __restrict__ g, int row0,
                                           int maxrow, int ld, int k0,
                                           char* lds, int wave, int lane) {
#pragma unroll
  for (int c = 0; c < 4; ++c) {
    int rbase = wave * 32 + c * 8;
    int row = rbase + (lane >> 3);
    int grow = row0 + row;
    grow = grow < maxrow ? grow : maxrow;
    int slot = (lane & 7) ^ (row & 7);
    const bf16* src = g + (size_t)grow * ld + k0 + slot * 8;
    __builtin_amdgcn_global_load_lds((const GLOBAL_AS unsigned int*)src,
                                     (LDS_AS unsigned int*)(lds + rbase * 128),
                                     16, 0, 0);
  }
}

// Single b128 fragment read (k-interleaved layout): granule = kk*4+g.
__device__ __forceinline__ short8v read_frag(const char* lds, int row, int kk, int lane) {
  int slot = (kk * 4 + (lane >> 4)) ^ (row & 7);
  return *reinterpret_cast<const short8v*>(lds + row * 128 + slot * 16);
}

// ---------- 256B-row staging (whole K=128, tail1) ----------
__device__ __forceinline__ void stage_tile256(const bf16* __restrict__ g, int row0,
                                              int maxrow, int ld,
                                              char* lds, int wave, int lane) {
#pragma unroll
  for (int c = 0; c < 8; ++c) {
    int rbase = wave * 32 + c * 4;
    int row = rbase + (lane >> 4);
    int grow = row0 + row;
    grow = grow < maxrow ? grow : maxrow;
    int slot = (lane & 15) ^ (row & 7);
    const bf16* src = g + (size_t)grow * ld + slot * 8;
    __builtin_amdgcn_global_load_lds((const GLOBAL_AS unsigned int*)src,
                                     (LDS_AS unsigned int*)(lds + rbase * 256),
                                     16, 0, 0);
  }
}

__device__ __forceinline__ short8v read_frag256(const char* lds, int row, int kk, int lane) {
  int slot = (kk * 4 + (lane >> 4)) ^ (row & 7);
  return *reinterpret_cast<const short8v*>(lds + row * 256 + slot * 16);
}

// shared sum-exp tree reduce + partial-sum write
__device__ __forceinline__ void reduce_write_ps(float srun[4][4], float* reds,
                                                float* ps, int slice, int tok0,
                                                int lane, int wr, int wc) {
#pragma unroll
  for (int off = 1; off < 16; off <<= 1)
#pragma unroll
    for (int m = 0; m < 4; ++m)
#pragma unroll
      for (int r = 0; r < 4; ++r) srun[m][r] += __shfl_xor(srun[m][r], off);
  __syncthreads();
  if (wc == 0 && (lane & 15) == 0) {
#pragma unroll
    for (int m = 0; m < 4; ++m)
#pragma unroll
      for (int r = 0; r < 4; ++r)
        reds[wr * 64 + m * 16 + (lane >> 4) * 4 + r] = srun[m][r];
  }
  __syncthreads();
  if (wc == 1 && (lane & 15) == 0) {
#pragma unroll
    for (int m = 0; m < 4; ++m)
#pragma unroll
      for (int r = 0; r < 4; ++r) {
        int row = wr * 64 + m * 16 + (lane >> 4) * 4 + r;
        ps[(size_t)slice * NTOK + tok0 + row] = reds[row] + srun[m][r];
      }
  }
}

// ---------- tail0 (H=512): 2-barrier, 33KB LDS, (256,3), 2D grid ----------
// No XCD remap: R8 showed remap raised FETCH 38->92MB and cost +16us.
__global__ __launch_bounds__(256, 3) void tail0_lse(
    const bf16* __restrict__ Ab, const bf16* __restrict__ W2b,
    float* __restrict__ ps) {
  __shared__ __align__(16) char As[128 * 128];
  __shared__ __align__(16) char Bs[128 * 128];
  __shared__ float reds[128];
  int tid = threadIdx.x;
  int lane = tid & 63, wave = tid >> 6;
  int wr = wave >> 1, wc = wave & 1;
  int tok0 = blockIdx.x * 128;
  int ys = blockIdx.y;
  int t_lo = (NT0 * ys) / JS0, t_hi = (NT0 * (ys + 1)) / JS0;
  float srun[4][4] = {};
  for (int jt = t_lo; jt < t_hi; ++jt) {
    int j0 = jt * 128;
    f32x4 acc[4][4] = {};
    for (int k0 = 0; k0 < H0S; k0 += 64) {
      __syncthreads();
      stage_tile(Ab, tok0, NTOK - 1, H0S, k0, As, wave, lane);
      stage_tile(W2b, j0, OSZ0 - 1, H0S, k0, Bs, wave, lane);
      __syncthreads();
#pragma unroll
      for (int kk = 0; kk < 2; ++kk) {
        short8v af[4], bfr[4];
#pragma unroll
        for (int m = 0; m < 4; ++m)
          af[m] = read_frag(As, wr * 64 + m * 16 + (lane & 15), kk, lane);
#pragma unroll
        for (int n = 0; n < 4; ++n)
          bfr[n] = read_frag(Bs, wc * 64 + n * 16 + (lane & 15), kk, lane);
#pragma unroll
        for (int m = 0; m < 4; ++m)
#pragma unroll
          for (int n = 0; n < 4; ++n)
            acc[m][n] = __builtin_amdgcn_mfma_f32_16x16x32_bf16(af[m], bfr[n], acc[m][n], 0, 0, 0);
      }
    }
#pragma unroll
    for (int m = 0; m < 4; ++m)
#pragma unroll
      for (int n = 0; n < 4; ++n) {
        int col = j0 + wc * 64 + n * 16 + (lane & 15);
        if (col < OSZ0) {
#pragma unroll
          for (int r = 0; r < 4; ++r) srun[m][r] += __expf(acc[m][n][r]);
        }
      }
  }
  reduce_write_ps(srun, reds, ps, ys, tok0, lane, wr, wc);
}

// ---------- tail1 (H=128): A-in-regs, dbuf B stream, counted vmcnt ----------
__device__ void tail1_body(const bf16* __restrict__ Ab, const bf16* __restrict__ W2b,
                           float* __restrict__ ps, char* lds) {
  char* buf0 = lds;             // 32 KB
  char* buf1 = lds + 32768;     // 32 KB
  float* reds = (float*)(lds + 65536);
  int tid = threadIdx.x;
  int lane = tid & 63, wave = tid >> 6;
  int wr = wave >> 1, wc = wave & 1;
  int tok0 = blockIdx.x * 128;
  int ys = blockIdx.y;
  int t_lo = (NT1 * ys) / JS1, t_hi = (NT1 * (ys + 1)) / JS1;
  int nt = t_hi - t_lo;

  stage_tile256(Ab, tok0, NTOK - 1, H1S, buf1, wave, lane);
  WAIT_VM(0); SCHED_FENCE();
  RAW_BAR();
  short8v afr[4][4];
#pragma unroll
  for (int kk = 0; kk < 4; ++kk)
#pragma unroll
    for (int m = 0; m < 4; ++m)
      afr[kk][m] = read_frag256(buf1, wr * 64 + m * 16 + (lane & 15), kk, lane);
  stage_tile256(W2b, t_lo * 128, OSZ1 - 1, H1S, buf0, wave, lane);
  WAIT_LGKM0(); SCHED_FENCE();   // A-frag reads done before buf1 reuse
  RAW_BAR();
  if (nt > 1) stage_tile256(W2b, (t_lo + 1) * 128, OSZ1 - 1, H1S, buf1, wave, lane);

  float srun[4][4] = {};
  for (int i = 0; i < nt; ++i) {
    char* cur = (i & 1) ? buf1 : buf0;
    if (i + 1 < nt) { WAIT_VM(8); } else { WAIT_VM(0); }
    SCHED_FENCE();
    RAW_BAR();
    int j0 = (t_lo + i) * 128;
    f32x4 acc[4][4] = {};
#pragma unroll
    for (int kk = 0; kk < 4; ++kk) {
      short8v bfr[4];
#pragma unroll
      for (int n = 0; n < 4; ++n)
        bfr[n] = read_frag256(cur, wc * 64 + n * 16 + (lane & 15), kk, lane);
#pragma unroll
      for (int m = 0; m < 4; ++m)
#pragma unroll
        for (int n = 0; n < 4; ++n)
          acc[m][n] = __builtin_amdgcn_mfma_f32_16x16x32_bf16(afr[kk][m], bfr[n], acc[m][n], 0, 0, 0);
    }
#pragma unroll
    for (int m = 0; m < 4; ++m)
#pragma unroll
      for (int n = 0; n < 4; ++n) {
        int col = j0 + wc * 64 + n * 16 + (lane & 15);
        if (col < OSZ1) {
#pragma unroll
          for (int r = 0; r < 4; ++r) srun[m][r] += __expf(acc[m][n][r]);
        }
      }
    SCHED_FENCE();
    RAW_BAR();
    if (i + 2 < nt) stage_tile256(W2b, (t_lo + i + 2) * 128, OSZ1 - 1, H1S, cur, wave, lane);
  }
  reduce_write_ps(srun, reds, ps, ys, tok0, lane, wr, wc);
}

__global__ __launch_bounds__(256, 2) void tail1_lse(
    const bf16* __restrict__ Ab, const bf16* __restrict__ W2b,
    float* __restrict__ ps) {
  __shared__ __align__(16) char lds[66048];
  tail1_body(Ab, W2b, ps, lds);
}

// ---------- fused projection GEMM: 2-barrier, 33KB, (256,3), XCD remap ----------
__global__ __launch_bounds__(256, 3) void proj_gemm(
    const bf16* __restrict__ A, const bf16* __restrict__ B,
    float* __restrict__ head, float* __restrict__ h0, bf16* __restrict__ h0b,
    float* __restrict__ h1, bf16* __restrict__ h1b, float* __restrict__ ps_head) {
  __shared__ __align__(16) char As[16384];
  __shared__ __align__(16) char Bs[16384];
  __shared__ float reds[128];
  int tid = threadIdx.x;
  int lane = tid & 63, wave = tid >> 6;
  int wr = wave >> 1, wc = wave & 1;
  int wgid = blockIdx.x;
  int cx = wgid & 7, w = wgid >> 3;    // 416 = 8 * 52
  int col_b = w >> 2;                  // 0..12
  int row_b = cx * 4 + (w & 3);        // 0..31
  int row0 = row_b * 128, col0 = col_b * 128;
  f32x4 acc[4][4] = {};
  for (int k0 = 0; k0 < DIM; k0 += 64) {
    __syncthreads();
    stage_tile(A, row0, NTOK - 1, DIM, k0, As, wave, lane);
    stage_tile(B, col0, NCAT - 1, DIM, k0, Bs, wave, lane);
    __syncthreads();
#pragma unroll
    for (int kk = 0; kk < 2; ++kk) {
      short8v af[4], bfr[4];
#pragma unroll
      for (int m = 0; m < 4; ++m)
        af[m] = read_frag(As, wr * 64 + m * 16 + (lane & 15), kk, lane);
#pragma unroll
      for (int n = 0; n < 4; ++n)
        bfr[n] = read_frag(Bs, wc * 64 + n * 16 + (lane & 15), kk, lane);
#pragma unroll
      for (int m = 0; m < 4; ++m)
#pragma unroll
        for (int n = 0; n < 4; ++n)
          acc[m][n] = __builtin_amdgcn_mfma_f32_16x16x32_bf16(af[m], bfr[n], acc[m][n], 0, 0, 0);
    }
  }
  float srun[4][4] = {};
#pragma unroll
  for (int m = 0; m < 4; ++m) {
    int row = row0 + wr * 64 + m * 16 + (lane >> 4) * 4;
#pragma unroll
    for (int n = 0; n < 4; ++n) {
      int col = col0 + wc * 64 + n * 16 + (lane & 15);
#pragma unroll
      for (int r = 0; r < 4; ++r) {
        float v = acc[m][n][r];
        if (col < NHEAD) {
          head[(size_t)(row + r) * NHEAD + col] = v;
          srun[m][r] += __expf(v);
        } else if (col >= 1024 && col < 1536) {
          int c = col - 1024;
          h0[(size_t)(row + r) * H0S + c] = v;
          h0b[(size_t)(row + r) * H0S + kperm(c)] = __float2bfloat16(v);
        } else if (col >= 1536) {
          int c = col - 1536;
          h1[(size_t)(row + r) * H1S + c] = v;
          h1b[(size_t)(row + r) * H1S + kperm(c)] = __float2bfloat16(v);
        }
      }
    }
  }
  if (col_b < HEADBLKS) {
    reduce_write_ps(srun, reds, ps_head, col_b, row0, lane, wr, wc);
  }
}

// ---------- finalize: one wave per token (fp32 tensors, non-interleaved) ----------
__global__ __launch_bounds__(256) void finalize2(
    const int* __restrict__ target, const float* __restrict__ head,
    const float* __restrict__ ps_head,
    const float* __restrict__ h0, const float* __restrict__ h1,
    const float* __restrict__ W2_0, const float* __restrict__ W2_1,
    const float* __restrict__ ps0, const float* __restrict__ ps1,
    float* __restrict__ out) {
  int warp = threadIdx.x >> 6, lane = threadIdx.x & 63;
  int i = blockIdx.x * 4 + warp;
  if (i >= NTOK) return;
  int t = target[i];
  float sh = 0.f;
#pragma unroll
  for (int s = 0; s < HEADBLKS; ++s) sh += ps_head[(size_t)s * NTOK + i];
  float lse_head = logf(sh);
  float res;
  if (t < C0LO) {
    res = head[(size_t)i * NHEAD + t] - lse_head;
  } else {
    int c = (t < C0HI) ? 0 : 1;
    int H = c ? H1S : H0S;
    int low = c ? C0HI : C0LO;
    const float* hv = (c ? h1 : h0) + (size_t)i * H;
    const float* wv = (c ? W2_1 : W2_0) + (size_t)(t - low) * H;
    float p = 0.f;
    for (int k = lane * 4; k < H; k += 256) {
      float4 a = *reinterpret_cast<const float4*>(hv + k);
      float4 b = *reinterpret_cast<const float4*>(wv + k);
      p += a.x * b.x + a.y * b.y + a.z * b.z + a.w * b.w;
    }
#pragma unroll
    for (int off = 32; off > 0; off >>= 1) p += __shfl_xor(p, off);
    const float* ps = c ? ps1 : ps0;
    int js = c ? JS1 : JS0;
    float S = 0.f;
    for (int s = 0; s < js; ++s) S += ps[(size_t)s * NTOK + i];
    float cl = head[(size_t)i * NHEAD + C0LO + c];
    res = (cl - lse_head) + (p - logf(S));
  }
  if (lane == 0) out[i] = res;
}

__global__ __launch_bounds__(256) void loss_kernel(float* __restrict__ out) {
  __shared__ float red[256];
  int tid = threadIdx.x;
  float s = 0.f;
  for (int j = tid; j < NTOK; j += 256) s += out[j];
  red[tid] = s; __syncthreads();
  for (int off = 128; off > 0; off >>= 1) {
    if (tid < off) red[tid] += red[tid + off];
    __syncthreads();
  }
  if (tid == 0) out[NTOK] = -red[0] / (float)NTOK;
}

extern "C" void kernel_launch(void* const* d_in, const int* in_sizes, int n_in,
                              void* d_out, int out_size, void* d_ws, size_t ws_size,
                              hipStream_t stream) {
  (void)in_sizes; (void)n_in; (void)out_size; (void)ws_size;
  const float* x = (const float*)d_in[0];
  const int* target = (const int*)d_in[1];
  const float* W_head = (const float*)d_in[2];
  const float* W1_0 = (const float*)d_in[3];
  const float* W2_0 = (const float*)d_in[4];
  const float* W1_1 = (const float*)d_in[5];
  const float* W2_1 = (const float*)d_in[6];
  float* out = (float*)d_out;

  char* w = (char*)d_ws;
  size_t off = 0;
  auto alloc = [&](size_t bytes) -> void* {
    void* p = w + off;
    off = (off + bytes + 255) & ~(size_t)255;
    return p;
  };
  bf16* xb   = (bf16*)alloc((size_t)NTOK * DIM * 2);
  bf16* Wcat = (bf16*)alloc((size_t)NCAT * DIM * 2);
  bf16* W20b = (bf16*)alloc((size_t)OSZ0 * H0S * 2);
  bf16* W21b = (bf16*)alloc((size_t)OSZ1 * H1S * 2);
  float* head = (float*)alloc((size_t)NTOK * NHEAD * 4);
  float* h0   = (float*)alloc((size_t)NTOK * H0S * 4);
  bf16*  h0b  = (bf16*)alloc((size_t)NTOK * H0S * 2);
  float* h1   = (float*)alloc((size_t)NTOK * H1S * 4);
  bf16*  h1b  = (bf16*)alloc((size_t)NTOK * H1S * 2);
  float* ps_head = (float*)alloc((size_t)HEADBLKS * NTOK * 4);
  float* ps0 = (float*)alloc((size_t)JS0 * NTOK * 4);
  float* ps1 = (float*)alloc((size_t)JS1 * NTOK * 4);

  dim3 blk(256);
  const long TOT8 = (long)NTOK * DIM / 8 + (long)NCAT * DIM / 8 +
                    (long)OSZ0 * H0S / 8 + (long)OSZ1 * H1S / 8;
  cvt_all<<<dim3((unsigned)((TOT8 + 255) / 256)), blk, 0, stream>>>(
      x, W_head, W1_0, W1_1, W2_0, W2_1, xb, Wcat, W20b, W21b);

  proj_gemm<<<dim3(416), blk, 0, stream>>>(
      xb, Wcat, head, h0, h0b, h1, h1b, ps_head);

  tail0_lse<<<dim3(NTOK / 128, JS0), blk, 0, stream>>>(h0b, W20b, ps0);
  tail1_lse<<<dim3(NTOK / 128, JS1), blk, 0, stream>>>(h1b, W21b, ps1);

  finalize2<<<dim3(NTOK / 4), blk, 0, stream>>>(target, head, ps_head, h0, h1,
                                                W2_0, W2_1, ps0, ps1, out);
  loss_kernel<<<1, blk, 0, stream>>>(out);
}

// Round 10
// 179.502 us; speedup vs baseline: 1.5177x; 1.0277x over previous
//
#include <hip/hip_runtime.h>
#include <hip/hip_bf16.h>
#include <math.h>

#define NTOK 4096
#define DIM 2048
#define NHEAD 1002
#define NCAT 1664
#define C0LO 1000
#define C0HI 10000
#define OSZ0 9000
#define OSZ1 40257
#define H0S 512
#define H1S 128
#define JS0 24               // tail0: 768 blocks, 3/CU @ 33KB LDS, (256,3)
#define JS1 16               // tail1: 512 blocks, 66KB LDS, 2/CU
#define HEADBLKS 8
#define NT0 71               // ceil(9000/128)
#define NT1 315              // ceil(40257/128)
#define PROJB 416            // proj compute blocks (8 XCD x 52)
#define CVTB 448             // W2-converter blocks riding the proj dispatch

typedef __attribute__((ext_vector_type(4))) short short4v;
typedef __attribute__((ext_vector_type(8))) short short8v;
typedef __attribute__((ext_vector_type(4))) float f32x4;
typedef __hip_bfloat16 bf16;

#define GLOBAL_AS __attribute__((address_space(1)))
#define LDS_AS __attribute__((address_space(3)))

#define RAW_BAR() __builtin_amdgcn_s_barrier()
#define SCHED_FENCE() __builtin_amdgcn_sched_barrier(0)
#define WAIT_VM(N) asm volatile("s_waitcnt vmcnt(" #N ")" ::: "memory")
#define WAIT_LGKM0() asm volatile("s_waitcnt lgkmcnt(0)" ::: "memory")

// k-interleave permutation within each 32-elem chunk (verified R9):
// pos(k) = g*8 + h*4 + e ; g=(k&15)>>2, h=(k>>4)&1, e=k&3.
__device__ __forceinline__ int kperm(int c) {
  return (c & ~31) | (((c & 15) >> 2) << 3) | (((c >> 4) & 1) << 2) | (c & 3);
}

// Gather-convert 8 bf16 (one 16B granule) of k-interleaved output.
__device__ __forceinline__ void cvt8(const float* s1, const float* s2, bf16* dst) {
  union { short8v v; bf16 h[8]; } u;
  float4 a = *reinterpret_cast<const float4*>(s1);
  float4 b = *reinterpret_cast<const float4*>(s2);
  u.h[0] = __float2bfloat16(a.x); u.h[1] = __float2bfloat16(a.y);
  u.h[2] = __float2bfloat16(a.z); u.h[3] = __float2bfloat16(a.w);
  u.h[4] = __float2bfloat16(b.x); u.h[5] = __float2bfloat16(b.y);
  u.h[6] = __float2bfloat16(b.z); u.h[7] = __float2bfloat16(b.w);
  *reinterpret_cast<short8v*>(dst) = u.v;
}

// ---------- cvt for xb + Wcat only (proj inputs); W2 handled in proj_plus ----------
__global__ __launch_bounds__(256) void cvt_xw(
    const float* __restrict__ x, const float* __restrict__ W_head,
    const float* __restrict__ W1_0, const float* __restrict__ W1_1,
    bf16* __restrict__ xb, bf16* __restrict__ Wcat) {
  const long NX = (long)NTOK * DIM / 8;
  const long NC = (long)NCAT * DIM / 8;
  long gid = (long)blockIdx.x * 256 + threadIdx.x;
  if (gid < NX) {
    long rel = gid * 8;
    long c1 = (rel & ~31L) + ((rel >> 3) & 3) * 4;
    cvt8(x + c1, x + c1 + 16, xb + rel);
  } else if (gid < NX + NC) {
    long rel = (gid - NX) * 8;
    int row = (int)(rel >> 11);
    long c1 = (rel & ~31L) + ((rel >> 3) & 3) * 4;
    int col = (int)(c1 & 2047);
    const float* srow = nullptr;
    if (row < NHEAD) srow = W_head + (long)row * DIM;
    else if (row < 1024) srow = nullptr;             // zero padding rows
    else if (row < 1536) srow = W1_0 + (long)(row - 1024) * DIM;
    else srow = W1_1 + (long)(row - 1536) * DIM;
    if (srow) {
      cvt8(srow + col, srow + col + 16, Wcat + rel);
    } else {
      union { short8v v; bf16 h[8]; } u;
#pragma unroll
      for (int e = 0; e < 8; ++e) u.h[e] = __float2bfloat16(0.f);
      *reinterpret_cast<short8v*>(Wcat + rel) = u.v;
    }
  }
}

// ---------- 128B-row staging (BK=64), 16B-slot XOR swizzle on source ----------
__device__ __forceinline__ void stage_tile(const bf16* __restrict__ g, int row0,
                                           int maxrow, int ld, int k0,
                                           char* lds, int wave, int lane) {
#pragma unroll
  for (int c = 0; c < 4; ++c) {
    int rbase = wave * 32 + c * 8;
    int row = rbase + (lane >> 3);
    int grow = row0 + row;
    grow = grow < maxrow ? grow : maxrow;
    int slot = (lane & 7) ^ (row & 7);
    const bf16* src = g + (size_t)grow * ld + k0 + slot * 8;
    __builtin_amdgcn_global_load_lds((const GLOBAL_AS unsigned int*)src,
                                     (LDS_AS unsigned int*)(lds + rbase * 128),
                                     16, 0, 0);
  }
}

// Single b128 fragment read (k-interleaved layout, verified R9).
__device__ __forceinline__ short8v read_frag(const char* lds, int row, int kk, int lane) {
  int slot = (kk * 4 + (lane >> 4)) ^ (row & 7);
  return *reinterpret_cast<const short8v*>(lds + row * 128 + slot * 16);
}

// ---------- 256B-row staging (whole K=128, tail1) ----------
__device__ __forceinline__ void stage_tile256(const bf16* __restrict__ g, int row0,
                                              int maxrow, int ld,
                                              char* lds, int wave, int lane) {
#pragma unroll
  for (int c = 0; c < 8; ++c) {
    int rbase = wave * 32 + c * 4;
    int row = rbase + (lane >> 4);
    int grow = row0 + row;
    grow = grow < maxrow ? grow : maxrow;
    int slot = (lane & 15) ^ (row & 7);
    const bf16* src = g + (size_t)grow * ld + slot * 8;
    __builtin_amdgcn_global_load_lds((const GLOBAL_AS unsigned int*)src,
                                     (LDS_AS unsigned int*)(lds + rbase * 256),
                                     16, 0, 0);
  }
}

__device__ __forceinline__ short8v read_frag256(const char* lds, int row, int kk, int lane) {
  int slot = (kk * 4 + (lane >> 4)) ^ (row & 7);
  return *reinterpret_cast<const short8v*>(lds + row * 256 + slot * 16);
}

// shared sum-exp tree reduce + partial-sum write
__device__ __forceinline__ void reduce_write_ps(float srun[4][4], float* reds,
                                                float* ps, int slice, int tok0,
                                                int lane, int wr, int wc) {
#pragma unroll
  for (int off = 1; off < 16; off <<= 1)
#pragma unroll
    for (int m = 0; m < 4; ++m)
#pragma unroll
      for (int r = 0; r < 4; ++r) srun[m][r] += __shfl_xor(srun[m][r], off);
  __syncthreads();
  if (wc == 0 && (lane & 15) == 0) {
#pragma unroll
    for (int m = 0; m < 4; ++m)
#pragma unroll
      for (int r = 0; r < 4; ++r)
        reds[wr * 64 + m * 16 + (lane >> 4) * 4 + r] = srun[m][r];
  }
  __syncthreads();
  if (wc == 1 && (lane & 15) == 0) {
#pragma unroll
    for (int m = 0; m < 4; ++m)
#pragma unroll
      for (int r = 0; r < 4; ++r) {
        int row = wr * 64 + m * 16 + (lane >> 4) * 4 + r;
        ps[(size_t)slice * NTOK + tok0 + row] = reds[row] + srun[m][r];
      }
  }
}

// ---------- tail0 (H=512): 2-barrier, 33KB LDS, (256,3), 2D grid ----------
__global__ __launch_bounds__(256, 3) void tail0_lse(
    const bf16* __restrict__ Ab, const bf16* __restrict__ W2b,
    float* __restrict__ ps) {
  __shared__ __align__(16) char As[128 * 128];
  __shared__ __align__(16) char Bs[128 * 128];
  __shared__ float reds[128];
  int tid = threadIdx.x;
  int lane = tid & 63, wave = tid >> 6;
  int wr = wave >> 1, wc = wave & 1;
  int tok0 = blockIdx.x * 128;
  int ys = blockIdx.y;
  int t_lo = (NT0 * ys) / JS0, t_hi = (NT0 * (ys + 1)) / JS0;
  float srun[4][4] = {};
  for (int jt = t_lo; jt < t_hi; ++jt) {
    int j0 = jt * 128;
    f32x4 acc[4][4] = {};
    for (int k0 = 0; k0 < H0S; k0 += 64) {
      __syncthreads();
      stage_tile(Ab, tok0, NTOK - 1, H0S, k0, As, wave, lane);
      stage_tile(W2b, j0, OSZ0 - 1, H0S, k0, Bs, wave, lane);
      __syncthreads();
#pragma unroll
      for (int kk = 0; kk < 2; ++kk) {
        short8v af[4], bfr[4];
#pragma unroll
        for (int m = 0; m < 4; ++m)
          af[m] = read_frag(As, wr * 64 + m * 16 + (lane & 15), kk, lane);
#pragma unroll
        for (int n = 0; n < 4; ++n)
          bfr[n] = read_frag(Bs, wc * 64 + n * 16 + (lane & 15), kk, lane);
#pragma unroll
        for (int m = 0; m < 4; ++m)
#pragma unroll
          for (int n = 0; n < 4; ++n)
            acc[m][n] = __builtin_amdgcn_mfma_f32_16x16x32_bf16(af[m], bfr[n], acc[m][n], 0, 0, 0);
      }
    }
#pragma unroll
    for (int m = 0; m < 4; ++m)
#pragma unroll
      for (int n = 0; n < 4; ++n) {
        int col = j0 + wc * 64 + n * 16 + (lane & 15);
        if (col < OSZ0) {
#pragma unroll
          for (int r = 0; r < 4; ++r) srun[m][r] += __expf(acc[m][n][r]);
        }
      }
  }
  reduce_write_ps(srun, reds, ps, ys, tok0, lane, wr, wc);
}

// ---------- tail1 (H=128): A-in-regs, dbuf B stream, counted vmcnt ----------
__device__ void tail1_body(const bf16* __restrict__ Ab, const bf16* __restrict__ W2b,
                           float* __restrict__ ps, char* lds) {
  char* buf0 = lds;             // 32 KB
  char* buf1 = lds + 32768;     // 32 KB
  float* reds = (float*)(lds + 65536);
  int tid = threadIdx.x;
  int lane = tid & 63, wave = tid >> 6;
  int wr = wave >> 1, wc = wave & 1;
  int tok0 = blockIdx.x * 128;
  int ys = blockIdx.y;
  int t_lo = (NT1 * ys) / JS1, t_hi = (NT1 * (ys + 1)) / JS1;
  int nt = t_hi - t_lo;

  stage_tile256(Ab, tok0, NTOK - 1, H1S, buf1, wave, lane);
  WAIT_VM(0); SCHED_FENCE();
  RAW_BAR();
  short8v afr[4][4];
#pragma unroll
  for (int kk = 0; kk < 4; ++kk)
#pragma unroll
    for (int m = 0; m < 4; ++m)
      afr[kk][m] = read_frag256(buf1, wr * 64 + m * 16 + (lane & 15), kk, lane);
  stage_tile256(W2b, t_lo * 128, OSZ1 - 1, H1S, buf0, wave, lane);
  WAIT_LGKM0(); SCHED_FENCE();   // A-frag reads done before buf1 reuse
  RAW_BAR();
  if (nt > 1) stage_tile256(W2b, (t_lo + 1) * 128, OSZ1 - 1, H1S, buf1, wave, lane);

  float srun[4][4] = {};
  for (int i = 0; i < nt; ++i) {
    char* cur = (i & 1) ? buf1 : buf0;
    if (i + 1 < nt) { WAIT_VM(8); } else { WAIT_VM(0); }
    SCHED_FENCE();
    RAW_BAR();
    int j0 = (t_lo + i) * 128;
    f32x4 acc[4][4] = {};
#pragma unroll
    for (int kk = 0; kk < 4; ++kk) {
      short8v bfr[4];
#pragma unroll
      for (int n = 0; n < 4; ++n)
        bfr[n] = read_frag256(cur, wc * 64 + n * 16 + (lane & 15), kk, lane);
#pragma unroll
      for (int m = 0; m < 4; ++m)
#pragma unroll
        for (int n = 0; n < 4; ++n)
          acc[m][n] = __builtin_amdgcn_mfma_f32_16x16x32_bf16(afr[kk][m], bfr[n], acc[m][n], 0, 0, 0);
    }
#pragma unroll
    for (int m = 0; m < 4; ++m)
#pragma unroll
      for (int n = 0; n < 4; ++n) {
        int col = j0 + wc * 64 + n * 16 + (lane & 15);
        if (col < OSZ1) {
#pragma unroll
          for (int r = 0; r < 4; ++r) srun[m][r] += __expf(acc[m][n][r]);
        }
      }
    SCHED_FENCE();
    RAW_BAR();
    if (i + 2 < nt) stage_tile256(W2b, (t_lo + i + 2) * 128, OSZ1 - 1, H1S, cur, wave, lane);
  }
  reduce_write_ps(srun, reds, ps, ys, tok0, lane, wr, wc);
}

__global__ __launch_bounds__(256, 2) void tail1_lse(
    const bf16* __restrict__ Ab, const bf16* __restrict__ W2b,
    float* __restrict__ ps) {
  __shared__ __align__(16) char lds[66048];
  tail1_body(Ab, W2b, ps, lds);
}

// ---------- proj GEMM + riding W2 converter blocks ----------
// Blocks [0,416): 2-barrier 33KB GEMM (R8/R9-verified). Blocks [416,864):
// grid-stride W2_0/W2_1 fp32->bf16 k-interleaved conversion. No sync needed:
// stream order guarantees W2b complete before tail kernels launch; proj
// compute blocks never touch W2b. Soaks the 1.6-blocks/CU underfill.
__global__ __launch_bounds__(256, 3) void proj_plus(
    const bf16* __restrict__ A, const bf16* __restrict__ B,
    const float* __restrict__ W2_0, const float* __restrict__ W2_1,
    bf16* __restrict__ W20b, bf16* __restrict__ W21b,
    float* __restrict__ head, float* __restrict__ h0, bf16* __restrict__ h0b,
    float* __restrict__ h1, bf16* __restrict__ h1b, float* __restrict__ ps_head) {
  __shared__ __align__(16) char As[16384];
  __shared__ __align__(16) char Bs[16384];
  __shared__ float reds[128];
  if (blockIdx.x >= PROJB) {
    // -------- converter role --------
    const long N20 = (long)OSZ0 * H0S / 8;   // 576000
    const long N21 = (long)OSZ1 * H1S / 8;   // 644112
    long idx = (long)(blockIdx.x - PROJB) * 256 + threadIdx.x;
    const long stride = (long)CVTB * 256;
    for (; idx < N20 + N21; idx += stride) {
      long rel; const float* srcb; bf16* dstb;
      if (idx < N20) { rel = idx * 8;          srcb = W2_0; dstb = W20b; }
      else           { rel = (idx - N20) * 8;  srcb = W2_1; dstb = W21b; }
      long c1 = (rel & ~31L) + ((rel >> 3) & 3) * 4;
      cvt8(srcb + c1, srcb + c1 + 16, dstb + rel);
    }
    return;
  }
  // -------- GEMM role --------
  int tid = threadIdx.x;
  int lane = tid & 63, wave = tid >> 6;
  int wr = wave >> 1, wc = wave & 1;
  int wgid = blockIdx.x;
  int cx = wgid & 7, w = wgid >> 3;    // 416 = 8 * 52
  int col_b = w >> 2;                  // 0..12
  int row_b = cx * 4 + (w & 3);        // 0..31
  int row0 = row_b * 128, col0 = col_b * 128;
  f32x4 acc[4][4] = {};
  for (int k0 = 0; k0 < DIM; k0 += 64) {
    __syncthreads();
    stage_tile(A, row0, NTOK - 1, DIM, k0, As, wave, lane);
    stage_tile(B, col0, NCAT - 1, DIM, k0, Bs, wave, lane);
    __syncthreads();
#pragma unroll
    for (int kk = 0; kk < 2; ++kk) {
      short8v af[4], bfr[4];
#pragma unroll
      for (int m = 0; m < 4; ++m)
        af[m] = read_frag(As, wr * 64 + m * 16 + (lane & 15), kk, lane);
#pragma unroll
      for (int n = 0; n < 4; ++n)
        bfr[n] = read_frag(Bs, wc * 64 + n * 16 + (lane & 15), kk, lane);
#pragma unroll
      for (int m = 0; m < 4; ++m)
#pragma unroll
        for (int n = 0; n < 4; ++n)
          acc[m][n] = __builtin_amdgcn_mfma_f32_16x16x32_bf16(af[m], bfr[n], acc[m][n], 0, 0, 0);
    }
  }
  float srun[4][4] = {};
#pragma unroll
  for (int m = 0; m < 4; ++m) {
    int row = row0 + wr * 64 + m * 16 + (lane >> 4) * 4;
#pragma unroll
    for (int n = 0; n < 4; ++n) {
      int col = col0 + wc * 64 + n * 16 + (lane & 15);
#pragma unroll
      for (int r = 0; r < 4; ++r) {
        float v = acc[m][n][r];
        if (col < NHEAD) {
          head[(size_t)(row + r) * NHEAD + col] = v;
          srun[m][r] += __expf(v);
        } else if (col >= 1024 && col < 1536) {
          int c = col - 1024;
          h0[(size_t)(row + r) * H0S + c] = v;
          h0b[(size_t)(row + r) * H0S + kperm(c)] = __float2bfloat16(v);
        } else if (col >= 1536) {
          int c = col - 1536;
          h1[(size_t)(row + r) * H1S + c] = v;
          h1b[(size_t)(row + r) * H1S + kperm(c)] = __float2bfloat16(v);
        }
      }
    }
  }
  if (col_b < HEADBLKS) {
    reduce_write_ps(srun, reds, ps_head, col_b, row0, lane, wr, wc);
  }
}

// ---------- finalize: one wave per token ----------
__global__ __launch_bounds__(256) void finalize2(
    const int* __restrict__ target, const float* __restrict__ head,
    const float* __restrict__ ps_head,
    const float* __restrict__ h0, const float* __restrict__ h1,
    const float* __restrict__ W2_0, const float* __restrict__ W2_1,
    const float* __restrict__ ps0, const float* __restrict__ ps1,
    float* __restrict__ out) {
  int warp = threadIdx.x >> 6, lane = threadIdx.x & 63;
  int i = blockIdx.x * 4 + warp;
  if (i >= NTOK) return;
  int t = target[i];
  float sh = 0.f;
#pragma unroll
  for (int s = 0; s < HEADBLKS; ++s) sh += ps_head[(size_t)s * NTOK + i];
  float lse_head = logf(sh);
  float res;
  if (t < C0LO) {
    res = head[(size_t)i * NHEAD + t] - lse_head;
  } else {
    int c = (t < C0HI) ? 0 : 1;
    int H = c ? H1S : H0S;
    int low = c ? C0HI : C0LO;
    const float* hv = (c ? h1 : h0) + (size_t)i * H;
    const float* wv = (c ? W2_1 : W2_0) + (size_t)(t - low) * H;
    float p = 0.f;
    for (int k = lane * 4; k < H; k += 256) {
      float4 a = *reinterpret_cast<const float4*>(hv + k);
      float4 b = *reinterpret_cast<const float4*>(wv + k);
      p += a.x * b.x + a.y * b.y + a.z * b.z + a.w * b.w;
    }
#pragma unroll
    for (int off = 32; off > 0; off >>= 1) p += __shfl_xor(p, off);
    const float* ps = c ? ps1 : ps0;
    int js = c ? JS1 : JS0;
    float S = 0.f;
    for (int s = 0; s < js; ++s) S += ps[(size_t)s * NTOK + i];
    float cl = head[(size_t)i * NHEAD + C0LO + c];
    res = (cl - lse_head) + (p - logf(S));
  }
  if (lane == 0) out[i] = res;
}

__global__ __launch_bounds__(256) void loss_kernel(float* __restrict__ out) {
  __shared__ float red[256];
  int tid = threadIdx.x;
  float s = 0.f;
  for (int j = tid; j < NTOK; j += 256) s += out[j];
  red[tid] = s; __syncthreads();
  for (int off = 128; off > 0; off >>= 1) {
    if (tid < off) red[tid] += red[tid + off];
    __syncthreads();
  }
  if (tid == 0) out[NTOK] = -red[0] / (float)NTOK;
}

extern "C" void kernel_launch(void* const* d_in, const int* in_sizes, int n_in,
                              void* d_out, int out_size, void* d_ws, size_t ws_size,
                              hipStream_t stream) {
  (void)in_sizes; (void)n_in; (void)out_size; (void)ws_size;
  const float* x = (const float*)d_in[0];
  const int* target = (const int*)d_in[1];
  const float* W_head = (const float*)d_in[2];
  const float* W1_0 = (const float*)d_in[3];
  const float* W2_0 = (const float*)d_in[4];
  const float* W1_1 = (const float*)d_in[5];
  const float* W2_1 = (const float*)d_in[6];
  float* out = (float*)d_out;

  char* w = (char*)d_ws;
  size_t off = 0;
  auto alloc = [&](size_t bytes) -> void* {
    void* p = w + off;
    off = (off + bytes + 255) & ~(size_t)255;
    return p;
  };
  bf16* xb   = (bf16*)alloc((size_t)NTOK * DIM * 2);
  bf16* Wcat = (bf16*)alloc((size_t)NCAT * DIM * 2);
  bf16* W20b = (bf16*)alloc((size_t)OSZ0 * H0S * 2);
  bf16* W21b = (bf16*)alloc((size_t)OSZ1 * H1S * 2);
  float* head = (float*)alloc((size_t)NTOK * NHEAD * 4);
  float* h0   = (float*)alloc((size_t)NTOK * H0S * 4);
  bf16*  h0b  = (bf16*)alloc((size_t)NTOK * H0S * 2);
  float* h1   = (float*)alloc((size_t)NTOK * H1S * 4);
  bf16*  h1b  = (bf16*)alloc((size_t)NTOK * H1S * 2);
  float* ps_head = (float*)alloc((size_t)HEADBLKS * NTOK * 4);
  float* ps0 = (float*)alloc((size_t)JS0 * NTOK * 4);
  float* ps1 = (float*)alloc((size_t)JS1 * NTOK * 4);

  dim3 blk(256);
  const long NXW = (long)NTOK * DIM / 8 + (long)NCAT * DIM / 8;
  cvt_xw<<<dim3((unsigned)((NXW + 255) / 256)), blk, 0, stream>>>(
      x, W_head, W1_0, W1_1, xb, Wcat);

  proj_plus<<<dim3(PROJB + CVTB), blk, 0, stream>>>(
      xb, Wcat, W2_0, W2_1, W20b, W21b, head, h0, h0b, h1, h1b, ps_head);

  tail0_lse<<<dim3(NTOK / 128, JS0), blk, 0, stream>>>(h0b, W20b, ps0);
  tail1_lse<<<dim3(NTOK / 128, JS1), blk, 0, stream>>>(h1b, W21b, ps1);

  finalize2<<<dim3(NTOK / 4), blk, 0, stream>>>(target, head, ps_head, h0, h1,
                                                W2_0, W2_1, ps0, ps1, out);
  loss_kernel<<<1, blk, 0, stream>>>(out);
}

// Round 11
// 176.387 us; speedup vs baseline: 1.5445x; 1.0177x over previous
//
#include <hip/hip_runtime.h>
#include <hip/hip_bf16.h>
#include <math.h>

#define NTOK 4096
#define DIM 2048
#define NHEAD 1002
#define NCAT 1664
#define C0LO 1000
#define C0HI 10000
#define OSZ0 9000
#define OSZ1 40257
#define H0S 512
#define H1S 128
#define JS0 16               // tail0: 512 blocks, 66KB LDS, 2/CU, pipelined
#define JS1 16               // tail1: 512 blocks, 66KB LDS, 2/CU
#define HEADBLKS 8
#define NT0 71               // ceil(9000/128)
#define NT1 315              // ceil(40257/128)
#define PROJB 416            // proj compute blocks (8 XCD x 52)
#define CVTB 352             // W2 converters; 416+352=768 = one residency wave @3/CU

typedef __attribute__((ext_vector_type(4))) short short4v;
typedef __attribute__((ext_vector_type(8))) short short8v;
typedef __attribute__((ext_vector_type(4))) float f32x4;
typedef __hip_bfloat16 bf16;

#define GLOBAL_AS __attribute__((address_space(1)))
#define LDS_AS __attribute__((address_space(3)))

#define RAW_BAR() __builtin_amdgcn_s_barrier()
#define SCHED_FENCE() __builtin_amdgcn_sched_barrier(0)
#define WAIT_VM(N) asm volatile("s_waitcnt vmcnt(" #N ")" ::: "memory")
#define WAIT_LGKM0() asm volatile("s_waitcnt lgkmcnt(0)" ::: "memory")

// k-interleave permutation within each 32-elem chunk (verified R9).
__device__ __forceinline__ int kperm(int c) {
  return (c & ~31) | (((c & 15) >> 2) << 3) | (((c >> 4) & 1) << 2) | (c & 3);
}

__device__ __forceinline__ void cvt8(const float* s1, const float* s2, bf16* dst) {
  union { short8v v; bf16 h[8]; } u;
  float4 a = *reinterpret_cast<const float4*>(s1);
  float4 b = *reinterpret_cast<const float4*>(s2);
  u.h[0] = __float2bfloat16(a.x); u.h[1] = __float2bfloat16(a.y);
  u.h[2] = __float2bfloat16(a.z); u.h[3] = __float2bfloat16(a.w);
  u.h[4] = __float2bfloat16(b.x); u.h[5] = __float2bfloat16(b.y);
  u.h[6] = __float2bfloat16(b.z); u.h[7] = __float2bfloat16(b.w);
  *reinterpret_cast<short8v*>(dst) = u.v;
}

// ---------- cvt for xb + Wcat (proj inputs) ----------
__global__ __launch_bounds__(256) void cvt_xw(
    const float* __restrict__ x, const float* __restrict__ W_head,
    const float* __restrict__ W1_0, const float* __restrict__ W1_1,
    bf16* __restrict__ xb, bf16* __restrict__ Wcat) {
  const long NX = (long)NTOK * DIM / 8;
  const long NC = (long)NCAT * DIM / 8;
  long gid = (long)blockIdx.x * 256 + threadIdx.x;
  if (gid < NX) {
    long rel = gid * 8;
    long c1 = (rel & ~31L) + ((rel >> 3) & 3) * 4;
    cvt8(x + c1, x + c1 + 16, xb + rel);
  } else if (gid < NX + NC) {
    long rel = (gid - NX) * 8;
    int row = (int)(rel >> 11);
    long c1 = (rel & ~31L) + ((rel >> 3) & 3) * 4;
    int col = (int)(c1 & 2047);
    const float* srow = nullptr;
    if (row < NHEAD) srow = W_head + (long)row * DIM;
    else if (row < 1024) srow = nullptr;             // zero padding rows
    else if (row < 1536) srow = W1_0 + (long)(row - 1024) * DIM;
    else srow = W1_1 + (long)(row - 1536) * DIM;
    if (srow) {
      cvt8(srow + col, srow + col + 16, Wcat + rel);
    } else {
      union { short8v v; bf16 h[8]; } u;
#pragma unroll
      for (int e = 0; e < 8; ++e) u.h[e] = __float2bfloat16(0.f);
      *reinterpret_cast<short8v*>(Wcat + rel) = u.v;
    }
  }
}

// ---------- 128B-row staging (BK=64), 16B-slot XOR swizzle on source ----------
__device__ __forceinline__ void stage_tile(const bf16* __restrict__ g, int row0,
                                           int maxrow, int ld, int k0,
                                           char* lds, int wave, int lane) {
#pragma unroll
  for (int c = 0; c < 4; ++c) {
    int rbase = wave * 32 + c * 8;
    int row = rbase + (lane >> 3);
    int grow = row0 + row;
    grow = grow < maxrow ? grow : maxrow;
    int slot = (lane & 7) ^ (row & 7);
    const bf16* src = g + (size_t)grow * ld + k0 + slot * 8;
    __builtin_amdgcn_global_load_lds((const GLOBAL_AS unsigned int*)src,
                                     (LDS_AS unsigned int*)(lds + rbase * 128),
                                     16, 0, 0);
  }
}

// Single b128 fragment read (k-interleaved layout, verified R9).
__device__ __forceinline__ short8v read_frag(const char* lds, int row, int kk, int lane) {
  int slot = (kk * 4 + (lane >> 4)) ^ (row & 7);
  return *reinterpret_cast<const short8v*>(lds + row * 128 + slot * 16);
}

// ---------- 256B-row staging (whole K=128, tail1) ----------
__device__ __forceinline__ void stage_tile256(const bf16* __restrict__ g, int row0,
                                              int maxrow, int ld,
                                              char* lds, int wave, int lane) {
#pragma unroll
  for (int c = 0; c < 8; ++c) {
    int rbase = wave * 32 + c * 4;
    int row = rbase + (lane >> 4);
    int grow = row0 + row;
    grow = grow < maxrow ? grow : maxrow;
    int slot = (lane & 15) ^ (row & 7);
    const bf16* src = g + (size_t)grow * ld + slot * 8;
    __builtin_amdgcn_global_load_lds((const GLOBAL_AS unsigned int*)src,
                                     (LDS_AS unsigned int*)(lds + rbase * 256),
                                     16, 0, 0);
  }
}

__device__ __forceinline__ short8v read_frag256(const char* lds, int row, int kk, int lane) {
  int slot = (kk * 4 + (lane >> 4)) ^ (row & 7);
  return *reinterpret_cast<const short8v*>(lds + row * 256 + slot * 16);
}

// shared sum-exp tree reduce + partial-sum write
__device__ __forceinline__ void reduce_write_ps(float srun[4][4], float* reds,
                                                float* ps, int slice, int tok0,
                                                int lane, int wr, int wc) {
#pragma unroll
  for (int off = 1; off < 16; off <<= 1)
#pragma unroll
    for (int m = 0; m < 4; ++m)
#pragma unroll
      for (int r = 0; r < 4; ++r) srun[m][r] += __shfl_xor(srun[m][r], off);
  __syncthreads();
  if (wc == 0 && (lane & 15) == 0) {
#pragma unroll
    for (int m = 0; m < 4; ++m)
#pragma unroll
      for (int r = 0; r < 4; ++r)
        reds[wr * 64 + m * 16 + (lane >> 4) * 4 + r] = srun[m][r];
  }
  __syncthreads();
  if (wc == 1 && (lane & 15) == 0) {
#pragma unroll
    for (int m = 0; m < 4; ++m)
#pragma unroll
      for (int r = 0; r < 4; ++r) {
        int row = wr * 64 + m * 16 + (lane >> 4) * 4 + r;
        ps[(size_t)slice * NTOK + tok0 + row] = reds[row] + srun[m][r];
      }
  }
}

// ---------- tail0 (H=512): min-2-phase dbuf pipeline (sync verified R5) ----------
// Flattened (j-tile, k-step) iteration; stage it+2 after computing it; counted
// vmcnt(8) keeps next tile's 8 loads in flight across the barrier.
__device__ void tail0_body(const bf16* __restrict__ Ab, const bf16* __restrict__ W2b,
                           float* __restrict__ ps, char* lds) {
  char* Abuf[2] = {lds, lds + 16384};
  char* Bbuf[2] = {lds + 32768, lds + 49152};
  float* reds = (float*)(lds + 65536);
  int tid = threadIdx.x;
  int lane = tid & 63, wave = tid >> 6;
  int wr = wave >> 1, wc = wave & 1;
  int tok0 = blockIdx.x * 128;
  int ys = blockIdx.y;
  int t_lo = (NT0 * ys) / JS0, t_hi = (NT0 * (ys + 1)) / JS0;
  int niter = (t_hi - t_lo) * 8;   // 8 k-steps per j-tile (H=512/64)

  stage_tile(Ab, tok0, NTOK - 1, H0S, 0, Abuf[0], wave, lane);
  stage_tile(W2b, t_lo * 128, OSZ0 - 1, H0S, 0, Bbuf[0], wave, lane);
  if (niter > 1) {
    stage_tile(Ab, tok0, NTOK - 1, H0S, 64, Abuf[1], wave, lane);
    stage_tile(W2b, t_lo * 128, OSZ0 - 1, H0S, 64, Bbuf[1], wave, lane);
  }
  float srun[4][4] = {};
  f32x4 acc[4][4];
  for (int it = 0; it < niter; ++it) {
    char* Ac = Abuf[it & 1];
    char* Bc = Bbuf[it & 1];
    if (it + 1 < niter) { WAIT_VM(8); } else { WAIT_VM(0); }
    SCHED_FENCE();
    RAW_BAR();
    int kst = it & 7;
    if (kst == 0) {
#pragma unroll
      for (int m = 0; m < 4; ++m)
#pragma unroll
        for (int n = 0; n < 4; ++n) acc[m][n] = f32x4{0.f, 0.f, 0.f, 0.f};
    }
#pragma unroll
    for (int kk = 0; kk < 2; ++kk) {
      short8v af[4], bfr[4];
#pragma unroll
      for (int m = 0; m < 4; ++m)
        af[m] = read_frag(Ac, wr * 64 + m * 16 + (lane & 15), kk, lane);
#pragma unroll
      for (int n = 0; n < 4; ++n)
        bfr[n] = read_frag(Bc, wc * 64 + n * 16 + (lane & 15), kk, lane);
#pragma unroll
      for (int m = 0; m < 4; ++m)
#pragma unroll
        for (int n = 0; n < 4; ++n)
          acc[m][n] = __builtin_amdgcn_mfma_f32_16x16x32_bf16(af[m], bfr[n], acc[m][n], 0, 0, 0);
    }
    if (kst == 7) {
      int j0 = (t_lo + (it >> 3)) * 128;
#pragma unroll
      for (int m = 0; m < 4; ++m)
#pragma unroll
        for (int n = 0; n < 4; ++n) {
          int col = j0 + wc * 64 + n * 16 + (lane & 15);
          if (col < OSZ0) {
#pragma unroll
            for (int r = 0; r < 4; ++r) srun[m][r] += __expf(acc[m][n][r]);
          }
        }
    }
    SCHED_FENCE();
    RAW_BAR();
    if (it + 2 < niter) {
      int it2 = it + 2;
      stage_tile(Ab, tok0, NTOK - 1, H0S, (it2 & 7) * 64, Ac, wave, lane);
      stage_tile(W2b, (t_lo + (it2 >> 3)) * 128, OSZ0 - 1, H0S, (it2 & 7) * 64, Bc, wave, lane);
    }
  }
  reduce_write_ps(srun, reds, ps, ys, tok0, lane, wr, wc);
}

__global__ __launch_bounds__(256, 2) void tail0_lse(
    const bf16* __restrict__ Ab, const bf16* __restrict__ W2b,
    float* __restrict__ ps) {
  __shared__ __align__(16) char lds[66048];
  tail0_body(Ab, W2b, ps, lds);
}

// ---------- tail1 (H=128): A-in-regs, dbuf B stream (R3-verified) ----------
__device__ void tail1_body(const bf16* __restrict__ Ab, const bf16* __restrict__ W2b,
                           float* __restrict__ ps, char* lds) {
  char* buf0 = lds;             // 32 KB
  char* buf1 = lds + 32768;     // 32 KB
  float* reds = (float*)(lds + 65536);
  int tid = threadIdx.x;
  int lane = tid & 63, wave = tid >> 6;
  int wr = wave >> 1, wc = wave & 1;
  int tok0 = blockIdx.x * 128;
  int ys = blockIdx.y;
  int t_lo = (NT1 * ys) / JS1, t_hi = (NT1 * (ys + 1)) / JS1;
  int nt = t_hi - t_lo;

  stage_tile256(Ab, tok0, NTOK - 1, H1S, buf1, wave, lane);
  WAIT_VM(0); SCHED_FENCE();
  RAW_BAR();
  short8v afr[4][4];
#pragma unroll
  for (int kk = 0; kk < 4; ++kk)
#pragma unroll
    for (int m = 0; m < 4; ++m)
      afr[kk][m] = read_frag256(buf1, wr * 64 + m * 16 + (lane & 15), kk, lane);
  stage_tile256(W2b, t_lo * 128, OSZ1 - 1, H1S, buf0, wave, lane);
  WAIT_LGKM0(); SCHED_FENCE();   // A-frag reads done before buf1 reuse
  RAW_BAR();
  if (nt > 1) stage_tile256(W2b, (t_lo + 1) * 128, OSZ1 - 1, H1S, buf1, wave, lane);

  float srun[4][4] = {};
  for (int i = 0; i < nt; ++i) {
    char* cur = (i & 1) ? buf1 : buf0;
    if (i + 1 < nt) { WAIT_VM(8); } else { WAIT_VM(0); }
    SCHED_FENCE();
    RAW_BAR();
    int j0 = (t_lo + i) * 128;
    f32x4 acc[4][4] = {};
#pragma unroll
    for (int kk = 0; kk < 4; ++kk) {
      short8v bfr[4];
#pragma unroll
      for (int n = 0; n < 4; ++n)
        bfr[n] = read_frag256(cur, wc * 64 + n * 16 + (lane & 15), kk, lane);
#pragma unroll
      for (int m = 0; m < 4; ++m)
#pragma unroll
        for (int n = 0; n < 4; ++n)
          acc[m][n] = __builtin_amdgcn_mfma_f32_16x16x32_bf16(afr[kk][m], bfr[n], acc[m][n], 0, 0, 0);
    }
#pragma unroll
    for (int m = 0; m < 4; ++m)
#pragma unroll
      for (int n = 0; n < 4; ++n) {
        int col = j0 + wc * 64 + n * 16 + (lane & 15);
        if (col < OSZ1) {
#pragma unroll
          for (int r = 0; r < 4; ++r) srun[m][r] += __expf(acc[m][n][r]);
        }
      }
    SCHED_FENCE();
    RAW_BAR();
    if (i + 2 < nt) stage_tile256(W2b, (t_lo + i + 2) * 128, OSZ1 - 1, H1S, cur, wave, lane);
  }
  reduce_write_ps(srun, reds, ps, ys, tok0, lane, wr, wc);
}

__global__ __launch_bounds__(256, 2) void tail1_lse(
    const bf16* __restrict__ Ab, const bf16* __restrict__ W2b,
    float* __restrict__ ps) {
  __shared__ __align__(16) char lds[66048];
  tail1_body(Ab, W2b, ps, lds);
}

// ---------- proj GEMM + riding W2 converter blocks (768 total = 1 wave) ----------
__global__ __launch_bounds__(256, 3) void proj_plus(
    const bf16* __restrict__ A, const bf16* __restrict__ B,
    const float* __restrict__ W2_0, const float* __restrict__ W2_1,
    bf16* __restrict__ W20b, bf16* __restrict__ W21b,
    float* __restrict__ head, float* __restrict__ h0, bf16* __restrict__ h0b,
    float* __restrict__ h1, bf16* __restrict__ h1b, float* __restrict__ ps_head) {
  __shared__ __align__(16) char As[16384];
  __shared__ __align__(16) char Bs[16384];
  __shared__ float reds[128];
  if (blockIdx.x >= PROJB) {
    // -------- converter role --------
    const long N20 = (long)OSZ0 * H0S / 8;   // 576000
    const long N21 = (long)OSZ1 * H1S / 8;   // 644112
    long idx = (long)(blockIdx.x - PROJB) * 256 + threadIdx.x;
    const long stride = (long)CVTB * 256;
    for (; idx < N20 + N21; idx += stride) {
      long rel; const float* srcb; bf16* dstb;
      if (idx < N20) { rel = idx * 8;          srcb = W2_0; dstb = W20b; }
      else           { rel = (idx - N20) * 8;  srcb = W2_1; dstb = W21b; }
      long c1 = (rel & ~31L) + ((rel >> 3) & 3) * 4;
      cvt8(srcb + c1, srcb + c1 + 16, dstb + rel);
    }
    return;
  }
  // -------- GEMM role --------
  int tid = threadIdx.x;
  int lane = tid & 63, wave = tid >> 6;
  int wr = wave >> 1, wc = wave & 1;
  int wgid = blockIdx.x;
  int cx = wgid & 7, w = wgid >> 3;    // 416 = 8 * 52
  int col_b = w >> 2;                  // 0..12
  int row_b = cx * 4 + (w & 3);        // 0..31
  int row0 = row_b * 128, col0 = col_b * 128;
  f32x4 acc[4][4] = {};
  for (int k0 = 0; k0 < DIM; k0 += 64) {
    __syncthreads();
    stage_tile(A, row0, NTOK - 1, DIM, k0, As, wave, lane);
    stage_tile(B, col0, NCAT - 1, DIM, k0, Bs, wave, lane);
    __syncthreads();
#pragma unroll
    for (int kk = 0; kk < 2; ++kk) {
      short8v af[4], bfr[4];
#pragma unroll
      for (int m = 0; m < 4; ++m)
        af[m] = read_frag(As, wr * 64 + m * 16 + (lane & 15), kk, lane);
#pragma unroll
      for (int n = 0; n < 4; ++n)
        bfr[n] = read_frag(Bs, wc * 64 + n * 16 + (lane & 15), kk, lane);
#pragma unroll
      for (int m = 0; m < 4; ++m)
#pragma unroll
        for (int n = 0; n < 4; ++n)
          acc[m][n] = __builtin_amdgcn_mfma_f32_16x16x32_bf16(af[m], bfr[n], acc[m][n], 0, 0, 0);
    }
  }
  float srun[4][4] = {};
#pragma unroll
  for (int m = 0; m < 4; ++m) {
    int row = row0 + wr * 64 + m * 16 + (lane >> 4) * 4;
#pragma unroll
    for (int n = 0; n < 4; ++n) {
      int col = col0 + wc * 64 + n * 16 + (lane & 15);
#pragma unroll
      for (int r = 0; r < 4; ++r) {
        float v = acc[m][n][r];
        if (col < NHEAD) {
          head[(size_t)(row + r) * NHEAD + col] = v;
          srun[m][r] += __expf(v);
        } else if (col >= 1024 && col < 1536) {
          int c = col - 1024;
          h0[(size_t)(row + r) * H0S + c] = v;
          h0b[(size_t)(row + r) * H0S + kperm(c)] = __float2bfloat16(v);
        } else if (col >= 1536) {
          int c = col - 1536;
          h1[(size_t)(row + r) * H1S + c] = v;
          h1b[(size_t)(row + r) * H1S + kperm(c)] = __float2bfloat16(v);
        }
      }
    }
  }
  if (col_b < HEADBLKS) {
    reduce_write_ps(srun, reds, ps_head, col_b, row0, lane, wr, wc);
  }
}

// ---------- finalize: one wave per token ----------
__global__ __launch_bounds__(256) void finalize2(
    const int* __restrict__ target, const float* __restrict__ head,
    const float* __restrict__ ps_head,
    const float* __restrict__ h0, const float* __restrict__ h1,
    const float* __restrict__ W2_0, const float* __restrict__ W2_1,
    const float* __restrict__ ps0, const float* __restrict__ ps1,
    float* __restrict__ out) {
  int warp = threadIdx.x >> 6, lane = threadIdx.x & 63;
  int i = blockIdx.x * 4 + warp;
  if (i >= NTOK) return;
  int t = target[i];
  float sh = 0.f;
#pragma unroll
  for (int s = 0; s < HEADBLKS; ++s) sh += ps_head[(size_t)s * NTOK + i];
  float lse_head = logf(sh);
  float res;
  if (t < C0LO) {
    res = head[(size_t)i * NHEAD + t] - lse_head;
  } else {
    int c = (t < C0HI) ? 0 : 1;
    int H = c ? H1S : H0S;
    int low = c ? C0HI : C0LO;
    const float* hv = (c ? h1 : h0) + (size_t)i * H;
    const float* wv = (c ? W2_1 : W2_0) + (size_t)(t - low) * H;
    float p = 0.f;
    for (int k = lane * 4; k < H; k += 256) {
      float4 a = *reinterpret_cast<const float4*>(hv + k);
      float4 b = *reinterpret_cast<const float4*>(wv + k);
      p += a.x * b.x + a.y * b.y + a.z * b.z + a.w * b.w;
    }
#pragma unroll
    for (int off = 32; off > 0; off >>= 1) p += __shfl_xor(p, off);
    const float* ps = c ? ps1 : ps0;
    int js = c ? JS1 : JS0;
    float S = 0.f;
    for (int s = 0; s < js; ++s) S += ps[(size_t)s * NTOK + i];
    float cl = head[(size_t)i * NHEAD + C0LO + c];
    res = (cl - lse_head) + (p - logf(S));
  }
  if (lane == 0) out[i] = res;
}

__global__ __launch_bounds__(256) void loss_kernel(float* __restrict__ out) {
  __shared__ float red[256];
  int tid = threadIdx.x;
  float s = 0.f;
  for (int j = tid; j < NTOK; j += 256) s += out[j];
  red[tid] = s; __syncthreads();
  for (int off = 128; off > 0; off >>= 1) {
    if (tid < off) red[tid] += red[tid + off];
    __syncthreads();
  }
  if (tid == 0) out[NTOK] = -red[0] / (float)NTOK;
}

extern "C" void kernel_launch(void* const* d_in, const int* in_sizes, int n_in,
                              void* d_out, int out_size, void* d_ws, size_t ws_size,
                              hipStream_t stream) {
  (void)in_sizes; (void)n_in; (void)out_size; (void)ws_size;
  const float* x = (const float*)d_in[0];
  const int* target = (const int*)d_in[1];
  const float* W_head = (const float*)d_in[2];
  const float* W1_0 = (const float*)d_in[3];
  const float* W2_0 = (const float*)d_in[4];
  const float* W1_1 = (const float*)d_in[5];
  const float* W2_1 = (const float*)d_in[6];
  float* out = (float*)d_out;

  char* w = (char*)d_ws;
  size_t off = 0;
  auto alloc = [&](size_t bytes) -> void* {
    void* p = w + off;
    off = (off + bytes + 255) & ~(size_t)255;
    return p;
  };
  bf16* xb   = (bf16*)alloc((size_t)NTOK * DIM * 2);
  bf16* Wcat = (bf16*)alloc((size_t)NCAT * DIM * 2);
  bf16* W20b = (bf16*)alloc((size_t)OSZ0 * H0S * 2);
  bf16* W21b = (bf16*)alloc((size_t)OSZ1 * H1S * 2);
  float* head = (float*)alloc((size_t)NTOK * NHEAD * 4);
  float* h0   = (float*)alloc((size_t)NTOK * H0S * 4);
  bf16*  h0b  = (bf16*)alloc((size_t)NTOK * H0S * 2);
  float* h1   = (float*)alloc((size_t)NTOK * H1S * 4);
  bf16*  h1b  = (bf16*)alloc((size_t)NTOK * H1S * 2);
  float* ps_head = (float*)alloc((size_t)HEADBLKS * NTOK * 4);
  float* ps0 = (float*)alloc((size_t)JS0 * NTOK * 4);
  float* ps1 = (float*)alloc((size_t)JS1 * NTOK * 4);

  dim3 blk(256);
  const long NXW = (long)NTOK * DIM / 8 + (long)NCAT * DIM / 8;
  cvt_xw<<<dim3((unsigned)((NXW + 255) / 256)), blk, 0, stream>>>(
      x, W_head, W1_0, W1_1, xb, Wcat);

  proj_plus<<<dim3(PROJB + CVTB), blk, 0, stream>>>(
      xb, Wcat, W2_0, W2_1, W20b, W21b, head, h0, h0b, h1, h1b, ps_head);

  tail0_lse<<<dim3(NTOK / 128, JS0), blk, 0, stream>>>(h0b, W20b, ps0);
  tail1_lse<<<dim3(NTOK / 128, JS1), blk, 0, stream>>>(h1b, W21b, ps1);

  finalize2<<<dim3(NTOK / 4), blk, 0, stream>>>(target, head, ps_head, h0, h1,
                                                W2_0, W2_1, ps0, ps1, out);
  loss_kernel<<<1, blk, 0, stream>>>(out);
}

// Round 12
// 174.055 us; speedup vs baseline: 1.5652x; 1.0134x over previous
//
#include <hip/hip_runtime.h>
#include <hip/hip_bf16.h>
#include <math.h>

#define NTOK 4096
#define DIM 2048
#define NHEAD 1002
#define NCAT 1664
#define C0LO 1000
#define C0HI 10000
#define OSZ0 9000
#define OSZ1 40257
#define H0S 512
#define H1S 128
#define JS0 32               // tail0: 1024 blocks, 24.5KB LDS, (256,4) -> 4/CU
#define JS1 24               // tail1: 768 blocks, 33KB LDS, (256,3) -> 3/CU
#define HEADBLKS 8
#define NT0 141              // ceil(9000/64)   (64-col j-tiles)
#define NT1 630              // ceil(40257/64)
#define PROJB 416            // proj compute blocks (8 XCD x 52)
#define CVTB 352             // W2 converters; 416+352=768 = one residency wave @3/CU

typedef __attribute__((ext_vector_type(4))) short short4v;
typedef __attribute__((ext_vector_type(8))) short short8v;
typedef __attribute__((ext_vector_type(4))) float f32x4;
typedef __hip_bfloat16 bf16;

#define GLOBAL_AS __attribute__((address_space(1)))
#define LDS_AS __attribute__((address_space(3)))

#define RAW_BAR() __builtin_amdgcn_s_barrier()
#define SCHED_FENCE() __builtin_amdgcn_sched_barrier(0)
#define WAIT_VM(N) asm volatile("s_waitcnt vmcnt(" #N ")" ::: "memory")
#define WAIT_LGKM0() asm volatile("s_waitcnt lgkmcnt(0)" ::: "memory")

// k-interleave permutation within each 32-elem chunk (verified R9).
__device__ __forceinline__ int kperm(int c) {
  return (c & ~31) | (((c & 15) >> 2) << 3) | (((c >> 4) & 1) << 2) | (c & 3);
}

__device__ __forceinline__ void cvt8(const float* s1, const float* s2, bf16* dst) {
  union { short8v v; bf16 h[8]; } u;
  float4 a = *reinterpret_cast<const float4*>(s1);
  float4 b = *reinterpret_cast<const float4*>(s2);
  u.h[0] = __float2bfloat16(a.x); u.h[1] = __float2bfloat16(a.y);
  u.h[2] = __float2bfloat16(a.z); u.h[3] = __float2bfloat16(a.w);
  u.h[4] = __float2bfloat16(b.x); u.h[5] = __float2bfloat16(b.y);
  u.h[6] = __float2bfloat16(b.z); u.h[7] = __float2bfloat16(b.w);
  *reinterpret_cast<short8v*>(dst) = u.v;
}

// ---------- cvt for xb + Wcat (proj inputs) ----------
__global__ __launch_bounds__(256) void cvt_xw(
    const float* __restrict__ x, const float* __restrict__ W_head,
    const float* __restrict__ W1_0, const float* __restrict__ W1_1,
    bf16* __restrict__ xb, bf16* __restrict__ Wcat) {
  const long NX = (long)NTOK * DIM / 8;
  const long NC = (long)NCAT * DIM / 8;
  long gid = (long)blockIdx.x * 256 + threadIdx.x;
  if (gid < NX) {
    long rel = gid * 8;
    long c1 = (rel & ~31L) + ((rel >> 3) & 3) * 4;
    cvt8(x + c1, x + c1 + 16, xb + rel);
  } else if (gid < NX + NC) {
    long rel = (gid - NX) * 8;
    int row = (int)(rel >> 11);
    long c1 = (rel & ~31L) + ((rel >> 3) & 3) * 4;
    int col = (int)(c1 & 2047);
    const float* srow = nullptr;
    if (row < NHEAD) srow = W_head + (long)row * DIM;
    else if (row < 1024) srow = nullptr;             // zero padding rows
    else if (row < 1536) srow = W1_0 + (long)(row - 1024) * DIM;
    else srow = W1_1 + (long)(row - 1536) * DIM;
    if (srow) {
      cvt8(srow + col, srow + col + 16, Wcat + rel);
    } else {
      union { short8v v; bf16 h[8]; } u;
#pragma unroll
      for (int e = 0; e < 8; ++e) u.h[e] = __float2bfloat16(0.f);
      *reinterpret_cast<short8v*>(Wcat + rel) = u.v;
    }
  }
}

// ---------- staging helpers (16B granules, XOR swizzle on source) ----------
// 128 rows x 128B (A tiles, BK=64)
__device__ __forceinline__ void stage_tile(const bf16* __restrict__ g, int row0,
                                           int maxrow, int ld, int k0,
                                           char* lds, int wave, int lane) {
#pragma unroll
  for (int c = 0; c < 4; ++c) {
    int rbase = wave * 32 + c * 8;
    int row = rbase + (lane >> 3);
    int grow = row0 + row;
    grow = grow < maxrow ? grow : maxrow;
    int slot = (lane & 7) ^ (row & 7);
    const bf16* src = g + (size_t)grow * ld + k0 + slot * 8;
    __builtin_amdgcn_global_load_lds((const GLOBAL_AS unsigned int*)src,
                                     (LDS_AS unsigned int*)(lds + rbase * 128),
                                     16, 0, 0);
  }
}

// 64 rows x 128B (tail0 B tiles, BN=64)
__device__ __forceinline__ void stage_tileB64(const bf16* __restrict__ g, int row0,
                                              int maxrow, int ld, int k0,
                                              char* lds, int wave, int lane) {
#pragma unroll
  for (int c = 0; c < 2; ++c) {
    int rbase = wave * 16 + c * 8;
    int row = rbase + (lane >> 3);
    int grow = row0 + row;
    grow = grow < maxrow ? grow : maxrow;
    int slot = (lane & 7) ^ (row & 7);
    const bf16* src = g + (size_t)grow * ld + k0 + slot * 8;
    __builtin_amdgcn_global_load_lds((const GLOBAL_AS unsigned int*)src,
                                     (LDS_AS unsigned int*)(lds + rbase * 128),
                                     16, 0, 0);
  }
}

// 128 rows x 256B (tail1 A, whole K=128)
__device__ __forceinline__ void stage_tile256(const bf16* __restrict__ g, int row0,
                                              int maxrow, int ld,
                                              char* lds, int wave, int lane) {
#pragma unroll
  for (int c = 0; c < 8; ++c) {
    int rbase = wave * 32 + c * 4;
    int row = rbase + (lane >> 4);
    int grow = row0 + row;
    grow = grow < maxrow ? grow : maxrow;
    int slot = (lane & 15) ^ (row & 7);
    const bf16* src = g + (size_t)grow * ld + slot * 8;
    __builtin_amdgcn_global_load_lds((const GLOBAL_AS unsigned int*)src,
                                     (LDS_AS unsigned int*)(lds + rbase * 256),
                                     16, 0, 0);
  }
}

// 64 rows x 256B (tail1 B tiles, BN=64): 4 issues/thread
__device__ __forceinline__ void stage_tile256_64(const bf16* __restrict__ g, int row0,
                                                 int maxrow, int ld,
                                                 char* lds, int wave, int lane) {
#pragma unroll
  for (int c = 0; c < 4; ++c) {
    int rbase = wave * 16 + c * 4;
    int row = rbase + (lane >> 4);
    int grow = row0 + row;
    grow = grow < maxrow ? grow : maxrow;
    int slot = (lane & 15) ^ (row & 7);
    const bf16* src = g + (size_t)grow * ld + slot * 8;
    __builtin_amdgcn_global_load_lds((const GLOBAL_AS unsigned int*)src,
                                     (LDS_AS unsigned int*)(lds + rbase * 256),
                                     16, 0, 0);
  }
}

// Single b128 fragment reads (k-interleaved layout, verified R9).
__device__ __forceinline__ short8v read_frag(const char* lds, int row, int kk, int lane) {
  int slot = (kk * 4 + (lane >> 4)) ^ (row & 7);
  return *reinterpret_cast<const short8v*>(lds + row * 128 + slot * 16);
}
__device__ __forceinline__ short8v read_frag256(const char* lds, int row, int kk, int lane) {
  int slot = (kk * 4 + (lane >> 4)) ^ (row & 7);
  return *reinterpret_cast<const short8v*>(lds + row * 256 + slot * 16);
}

// shared sum-exp tree reduce + partial-sum write (row layout unchanged)
__device__ __forceinline__ void reduce_write_ps(float srun[4][4], float* reds,
                                                float* ps, int slice, int tok0,
                                                int lane, int wr, int wc) {
#pragma unroll
  for (int off = 1; off < 16; off <<= 1)
#pragma unroll
    for (int m = 0; m < 4; ++m)
#pragma unroll
      for (int r = 0; r < 4; ++r) srun[m][r] += __shfl_xor(srun[m][r], off);
  __syncthreads();
  if (wc == 0 && (lane & 15) == 0) {
#pragma unroll
    for (int m = 0; m < 4; ++m)
#pragma unroll
      for (int r = 0; r < 4; ++r)
        reds[wr * 64 + m * 16 + (lane >> 4) * 4 + r] = srun[m][r];
  }
  __syncthreads();
  if (wc == 1 && (lane & 15) == 0) {
#pragma unroll
    for (int m = 0; m < 4; ++m)
#pragma unroll
      for (int r = 0; r < 4; ++r) {
        int row = wr * 64 + m * 16 + (lane >> 4) * 4 + r;
        ps[(size_t)slice * NTOK + tok0 + row] = reds[row] + srun[m][r];
      }
  }
}

// ---------- tail0 (H=512): BM128 x BN64, 2-barrier, 24.5KB LDS, (256,4) ----------
// acc[4][2] = 32 VGPR (vs 64 at BN=128) -> reg need ~120 <= 128 budget @4 waves/EU.
__global__ __launch_bounds__(256, 4) void tail0_lse(
    const bf16* __restrict__ Ab, const bf16* __restrict__ W2b,
    float* __restrict__ ps) {
  __shared__ __align__(16) char As[16384];
  __shared__ __align__(16) char Bs[8192];
  __shared__ float reds[128];
  int tid = threadIdx.x;
  int lane = tid & 63, wave = tid >> 6;
  int wr = wave >> 1, wc = wave & 1;
  int tok0 = blockIdx.x * 128;
  int ys = blockIdx.y;
  int t_lo = (NT0 * ys) / JS0, t_hi = (NT0 * (ys + 1)) / JS0;
  float srun[4][4] = {};
  for (int jt = t_lo; jt < t_hi; ++jt) {
    int j0 = jt * 64;
    f32x4 acc[4][2] = {};
    for (int k0 = 0; k0 < H0S; k0 += 64) {
      __syncthreads();
      stage_tile(Ab, tok0, NTOK - 1, H0S, k0, As, wave, lane);
      stage_tileB64(W2b, j0, OSZ0 - 1, H0S, k0, Bs, wave, lane);
      __syncthreads();
#pragma unroll
      for (int kk = 0; kk < 2; ++kk) {
        short8v af[4], bfr[2];
#pragma unroll
        for (int m = 0; m < 4; ++m)
          af[m] = read_frag(As, wr * 64 + m * 16 + (lane & 15), kk, lane);
#pragma unroll
        for (int n = 0; n < 2; ++n)
          bfr[n] = read_frag(Bs, wc * 32 + n * 16 + (lane & 15), kk, lane);
#pragma unroll
        for (int m = 0; m < 4; ++m)
#pragma unroll
          for (int n = 0; n < 2; ++n)
            acc[m][n] = __builtin_amdgcn_mfma_f32_16x16x32_bf16(af[m], bfr[n], acc[m][n], 0, 0, 0);
      }
    }
#pragma unroll
    for (int m = 0; m < 4; ++m)
#pragma unroll
      for (int n = 0; n < 2; ++n) {
        int col = j0 + wc * 32 + n * 16 + (lane & 15);
        if (col < OSZ0) {
#pragma unroll
          for (int r = 0; r < 4; ++r) srun[m][r] += __expf(acc[m][n][r]);
        }
      }
  }
  reduce_write_ps(srun, reds, ps, ys, tok0, lane, wr, wc);
}

// ---------- tail1 (H=128): A-in-regs, BN=64 dbuf B stream, counted vmcnt ----------
// A staged across lds[0..32KB] then consumed to regs (LGKM fence + barrier
// BEFORE first B-stage overwrites it). B tiles 16KB, 4 loads/thread -> vmcnt(4).
__device__ void tail1_body(const bf16* __restrict__ Ab, const bf16* __restrict__ W2b,
                           float* __restrict__ ps, char* lds) {
  char* buf0 = lds;             // 16 KB
  char* buf1 = lds + 16384;     // 16 KB
  float* reds = (float*)(lds + 32768);
  int tid = threadIdx.x;
  int lane = tid & 63, wave = tid >> 6;
  int wr = wave >> 1, wc = wave & 1;
  int tok0 = blockIdx.x * 128;
  int ys = blockIdx.y;
  int t_lo = (NT1 * ys) / JS1, t_hi = (NT1 * (ys + 1)) / JS1;
  int nt = t_hi - t_lo;

  // Stage A (128 tok x 256B) into the combined buffer space; consume to regs.
  stage_tile256(Ab, tok0, NTOK - 1, H1S, lds, wave, lane);
  WAIT_VM(0); SCHED_FENCE();
  RAW_BAR();
  short8v afr[4][4];  // [kk][m]
#pragma unroll
  for (int kk = 0; kk < 4; ++kk)
#pragma unroll
    for (int m = 0; m < 4; ++m)
      afr[kk][m] = read_frag256(lds, wr * 64 + m * 16 + (lane & 15), kk, lane);
  WAIT_LGKM0(); SCHED_FENCE();   // all afr reads complete...
  RAW_BAR();                     // ...in every wave, before B overwrites A
  stage_tile256_64(W2b, t_lo * 64, OSZ1 - 1, H1S, buf0, wave, lane);
  if (nt > 1) stage_tile256_64(W2b, (t_lo + 1) * 64, OSZ1 - 1, H1S, buf1, wave, lane);

  float srun[4][4] = {};
  for (int i = 0; i < nt; ++i) {
    char* cur = (i & 1) ? buf1 : buf0;
    if (i + 1 < nt) { WAIT_VM(4); } else { WAIT_VM(0); }
    SCHED_FENCE();
    RAW_BAR();
    int j0 = (t_lo + i) * 64;
    f32x4 acc[4][2] = {};
#pragma unroll
    for (int kk = 0; kk < 4; ++kk) {
      short8v bfr[2];
#pragma unroll
      for (int n = 0; n < 2; ++n)
        bfr[n] = read_frag256(cur, wc * 32 + n * 16 + (lane & 15), kk, lane);
#pragma unroll
      for (int m = 0; m < 4; ++m)
#pragma unroll
        for (int n = 0; n < 2; ++n)
          acc[m][n] = __builtin_amdgcn_mfma_f32_16x16x32_bf16(afr[kk][m], bfr[n], acc[m][n], 0, 0, 0);
    }
#pragma unroll
    for (int m = 0; m < 4; ++m)
#pragma unroll
      for (int n = 0; n < 2; ++n) {
        int col = j0 + wc * 32 + n * 16 + (lane & 15);
        if (col < OSZ1) {
#pragma unroll
          for (int r = 0; r < 4; ++r) srun[m][r] += __expf(acc[m][n][r]);
        }
      }
    SCHED_FENCE();
    RAW_BAR();
    if (i + 2 < nt) stage_tile256_64(W2b, (t_lo + i + 2) * 64, OSZ1 - 1, H1S, cur, wave, lane);
  }
  reduce_write_ps(srun, reds, ps, ys, tok0, lane, wr, wc);
}

__global__ __launch_bounds__(256, 3) void tail1_lse(
    const bf16* __restrict__ Ab, const bf16* __restrict__ W2b,
    float* __restrict__ ps) {
  __shared__ __align__(16) char lds[33280];
  tail1_body(Ab, W2b, ps, lds);
}

// ---------- proj GEMM + riding W2 converter blocks (768 total = 1 wave) ----------
__global__ __launch_bounds__(256, 3) void proj_plus(
    const bf16* __restrict__ A, const bf16* __restrict__ B,
    const float* __restrict__ W2_0, const float* __restrict__ W2_1,
    bf16* __restrict__ W20b, bf16* __restrict__ W21b,
    float* __restrict__ head, float* __restrict__ h0, bf16* __restrict__ h0b,
    float* __restrict__ h1, bf16* __restrict__ h1b, float* __restrict__ ps_head) {
  __shared__ __align__(16) char As[16384];
  __shared__ __align__(16) char Bs[16384];
  __shared__ float reds[128];
  if (blockIdx.x >= PROJB) {
    // -------- converter role --------
    const long N20 = (long)OSZ0 * H0S / 8;   // 576000
    const long N21 = (long)OSZ1 * H1S / 8;   // 644112
    long idx = (long)(blockIdx.x - PROJB) * 256 + threadIdx.x;
    const long stride = (long)CVTB * 256;
    for (; idx < N20 + N21; idx += stride) {
      long rel; const float* srcb; bf16* dstb;
      if (idx < N20) { rel = idx * 8;          srcb = W2_0; dstb = W20b; }
      else           { rel = (idx - N20) * 8;  srcb = W2_1; dstb = W21b; }
      long c1 = (rel & ~31L) + ((rel >> 3) & 3) * 4;
      cvt8(srcb + c1, srcb + c1 + 16, dstb + rel);
    }
    return;
  }
  // -------- GEMM role --------
  int tid = threadIdx.x;
  int lane = tid & 63, wave = tid >> 6;
  int wr = wave >> 1, wc = wave & 1;
  int wgid = blockIdx.x;
  int cx = wgid & 7, w = wgid >> 3;    // 416 = 8 * 52
  int col_b = w >> 2;                  // 0..12
  int row_b = cx * 4 + (w & 3);        // 0..31
  int row0 = row_b * 128, col0 = col_b * 128;
  f32x4 acc[4][4] = {};
  for (int k0 = 0; k0 < DIM; k0 += 64) {
    __syncthreads();
    stage_tile(A, row0, NTOK - 1, DIM, k0, As, wave, lane);
    stage_tile(B, col0, NCAT - 1, DIM, k0, Bs, wave, lane);
    __syncthreads();
#pragma unroll
    for (int kk = 0; kk < 2; ++kk) {
      short8v af[4], bfr[4];
#pragma unroll
      for (int m = 0; m < 4; ++m)
        af[m] = read_frag(As, wr * 64 + m * 16 + (lane & 15), kk, lane);
#pragma unroll
      for (int n = 0; n < 4; ++n)
        bfr[n] = read_frag(Bs, wc * 64 + n * 16 + (lane & 15), kk, lane);
#pragma unroll
      for (int m = 0; m < 4; ++m)
#pragma unroll
        for (int n = 0; n < 4; ++n)
          acc[m][n] = __builtin_amdgcn_mfma_f32_16x16x32_bf16(af[m], bfr[n], acc[m][n], 0, 0, 0);
    }
  }
  float srun[4][4] = {};
#pragma unroll
  for (int m = 0; m < 4; ++m) {
    int row = row0 + wr * 64 + m * 16 + (lane >> 4) * 4;
#pragma unroll
    for (int n = 0; n < 4; ++n) {
      int col = col0 + wc * 64 + n * 16 + (lane & 15);
#pragma unroll
      for (int r = 0; r < 4; ++r) {
        float v = acc[m][n][r];
        if (col < NHEAD) {
          head[(size_t)(row + r) * NHEAD + col] = v;
          srun[m][r] += __expf(v);
        } else if (col >= 1024 && col < 1536) {
          int c = col - 1024;
          h0[(size_t)(row + r) * H0S + c] = v;
          h0b[(size_t)(row + r) * H0S + kperm(c)] = __float2bfloat16(v);
        } else if (col >= 1536) {
          int c = col - 1536;
          h1[(size_t)(row + r) * H1S + c] = v;
          h1b[(size_t)(row + r) * H1S + kperm(c)] = __float2bfloat16(v);
        }
      }
    }
  }
  if (col_b < HEADBLKS) {
    reduce_write_ps(srun, reds, ps_head, col_b, row0, lane, wr, wc);
  }
}

// ---------- finalize: one wave per token ----------
__global__ __launch_bounds__(256) void finalize2(
    const int* __restrict__ target, const float* __restrict__ head,
    const float* __restrict__ ps_head,
    const float* __restrict__ h0, const float* __restrict__ h1,
    const float* __restrict__ W2_0, const float* __restrict__ W2_1,
    const float* __restrict__ ps0, const float* __restrict__ ps1,
    float* __restrict__ out) {
  int warp = threadIdx.x >> 6, lane = threadIdx.x & 63;
  int i = blockIdx.x * 4 + warp;
  if (i >= NTOK) return;
  int t = target[i];
  float sh = 0.f;
#pragma unroll
  for (int s = 0; s < HEADBLKS; ++s) sh += ps_head[(size_t)s * NTOK + i];
  float lse_head = logf(sh);
  float res;
  if (t < C0LO) {
    res = head[(size_t)i * NHEAD + t] - lse_head;
  } else {
    int c = (t < C0HI) ? 0 : 1;
    int H = c ? H1S : H0S;
    int low = c ? C0HI : C0LO;
    const float* hv = (c ? h1 : h0) + (size_t)i * H;
    const float* wv = (c ? W2_1 : W2_0) + (size_t)(t - low) * H;
    float p = 0.f;
    for (int k = lane * 4; k < H; k += 256) {
      float4 a = *reinterpret_cast<const float4*>(hv + k);
      float4 b = *reinterpret_cast<const float4*>(wv + k);
      p += a.x * b.x + a.y * b.y + a.z * b.z + a.w * b.w;
    }
#pragma unroll
    for (int off = 32; off > 0; off >>= 1) p += __shfl_xor(p, off);
    const float* ps = c ? ps1 : ps0;
    int js = c ? JS1 : JS0;   // 24 : 32
    float S = 0.f;
    for (int s = 0; s < js; ++s) S += ps[(size_t)s * NTOK + i];
    float cl = head[(size_t)i * NHEAD + C0LO + c];
    res = (cl - lse_head) + (p - logf(S));
  }
  if (lane == 0) out[i] = res;
}

__global__ __launch_bounds__(256) void loss_kernel(float* __restrict__ out) {
  __shared__ float red[256];
  int tid = threadIdx.x;
  float s = 0.f;
  for (int j = tid; j < NTOK; j += 256) s += out[j];
  red[tid] = s; __syncthreads();
  for (int off = 128; off > 0; off >>= 1) {
    if (tid < off) red[tid] += red[tid + off];
    __syncthreads();
  }
  if (tid == 0) out[NTOK] = -red[0] / (float)NTOK;
}

extern "C" void kernel_launch(void* const* d_in, const int* in_sizes, int n_in,
                              void* d_out, int out_size, void* d_ws, size_t ws_size,
                              hipStream_t stream) {
  (void)in_sizes; (void)n_in; (void)out_size; (void)ws_size;
  const float* x = (const float*)d_in[0];
  const int* target = (const int*)d_in[1];
  const float* W_head = (const float*)d_in[2];
  const float* W1_0 = (const float*)d_in[3];
  const float* W2_0 = (const float*)d_in[4];
  const float* W1_1 = (const float*)d_in[5];
  const float* W2_1 = (const float*)d_in[6];
  float* out = (float*)d_out;

  char* w = (char*)d_ws;
  size_t off = 0;
  auto alloc = [&](size_t bytes) -> void* {
    void* p = w + off;
    off = (off + bytes + 255) & ~(size_t)255;
    return p;
  };
  bf16* xb   = (bf16*)alloc((size_t)NTOK * DIM * 2);
  bf16* Wcat = (bf16*)alloc((size_t)NCAT * DIM * 2);
  bf16* W20b = (bf16*)alloc((size_t)OSZ0 * H0S * 2);
  bf16* W21b = (bf16*)alloc((size_t)OSZ1 * H1S * 2);
  float* head = (float*)alloc((size_t)NTOK * NHEAD * 4);
  float* h0   = (float*)alloc((size_t)NTOK * H0S * 4);
  bf16*  h0b  = (bf16*)alloc((size_t)NTOK * H0S * 2);
  float* h1   = (float*)alloc((size_t)NTOK * H1S * 4);
  bf16*  h1b  = (bf16*)alloc((size_t)NTOK * H1S * 2);
  float* ps_head = (float*)alloc((size_t)HEADBLKS * NTOK * 4);
  float* ps0 = (float*)alloc((size_t)JS0 * NTOK * 4);
  float* ps1 = (float*)alloc((size_t)JS1 * NTOK * 4);

  dim3 blk(256);
  const long NXW = (long)NTOK * DIM / 8 + (long)NCAT * DIM / 8;
  cvt_xw<<<dim3((unsigned)((NXW + 255) / 256)), blk, 0, stream>>>(
      x, W_head, W1_0, W1_1, xb, Wcat);

  proj_plus<<<dim3(PROJB + CVTB), blk, 0, stream>>>(
      xb, Wcat, W2_0, W2_1, W20b, W21b, head, h0, h0b, h1, h1b, ps_head);

  tail0_lse<<<dim3(NTOK / 128, JS0), blk, 0, stream>>>(h0b, W20b, ps0);
  tail1_lse<<<dim3(NTOK / 128, JS1), blk, 0, stream>>>(h1b, W21b, ps1);

  finalize2<<<dim3(NTOK / 4), blk, 0, stream>>>(target, head, ps_head, h0, h1,
                                                W2_0, W2_1, ps0, ps1, out);
  loss_kernel<<<1, blk, 0, stream>>>(out);
}